// Round 2
// baseline (1486.461 us; speedup 1.0000x reference)
//
#include <hip/hip_runtime.h>
#include <math.h>

#define BB   16
#define NN   32768
#define GG   128
#define KK   64
#define EDD  384
#define NT1  1024
#define PPT  32   // NN / NT1

// ---- workspace layout (float offsets) ----
#define WS_GC     0          // [16][2][3]      = 96     (c0, cm per batch)
#define WS_LOCAL  96         // [32][64][3]     = 6144   (local coords per group)
#define WS_F2     6240       // [32][256][64]   = 524288
#define WS_FG     530528     // [32][256]       = 8192
#define WS_F4     538720     // [32][512][64]   = 1048576
#define WS_TOK    1587296    // [32][384]       = 12288
// total = 1,599,584 floats = ~6.4 MB

__device__ __forceinline__ float sq3(float a, float b, float c) {
  // matches np: ((a*a + b*b) + c*c), no FMA contraction
  return __fadd_rn(__fadd_rn(__fmul_rn(a, a), __fmul_rn(b, b)), __fmul_rn(c, c));
}
__device__ __forceinline__ float dot3(float ax, float ay, float az,
                                      float bx, float by, float bz) {
  return __fadd_rn(__fadd_rn(__fmul_rn(ax, bx), __fmul_rn(ay, by)), __fmul_rn(az, bz));
}

// ---------------------------------------------------------------------------
// Kernel 1: FPS (127 sequential argmax rounds) + morton-m + centroid output.
// One block per batch. dist/x/y in VGPRs (96 data regs), z in LDS (128 KiB).
// __launch_bounds__(1024,4): 4 waves/EU -> VGPR cap 128 (LDS caps us at
// 1 block/CU regardless, so there is no occupancy downside).
// R1 fix: previous version had x/y/z arrays spilled to scratch (VGPR=64),
// making every round re-read 393 KB/block through L2 -> 7 us/round.
// ---------------------------------------------------------------------------
__global__ void __launch_bounds__(NT1, 4) k_fps(const float* __restrict__ points,
                                                float* __restrict__ out,
                                                float* __restrict__ ws) {
  extern __shared__ float smem[];
  float* zsh   = smem;                       // [NN]
  float* red_d = smem + NN;                  // [16]
  int*   red_i = (int*)(smem + NN + 16);     // [16]
  float* cur   = smem + NN + 32;             // [3]
  float* cent  = smem + NN + 36;             // [GG*3]
  float* darr  = smem + NN + 420;            // [GG]
  int*   msh   = (int*)(smem + NN + 548);    // [1]

  const int b = blockIdx.x;
  const int t = threadIdx.x;
  const float* P = points + (size_t)b * NN * 3;

  float x[PPT], y[PPT], dist[PPT];
#pragma unroll
  for (int j = 0; j < PPT; ++j) {
    int p = t + j * NT1;
    x[j] = P[p * 3 + 0];
    y[j] = P[p * 3 + 1];
    zsh[p] = P[p * 3 + 2];
    dist[j] = INFINITY;
  }
  if (t == 0) {  // first centroid is point 0 (FPS init far=0)
    float z0 = P[2];
    cur[0] = x[0]; cur[1] = y[0]; cur[2] = z0;
    cent[0] = x[0]; cent[1] = y[0]; cent[2] = z0;
  }
  __syncthreads();

  for (int it = 1; it < GG; ++it) {
    float cx = cur[0], cy = cur[1], cz = cur[2];
    float bd = -1.0f; int bj = 0;
#pragma unroll
    for (int j = 0; j < PPT; ++j) {
      float dx = __fsub_rn(x[j], cx);
      float dy = __fsub_rn(y[j], cy);
      float dz = __fsub_rn(zsh[t + j * NT1], cz);
      float d  = __fadd_rn(__fadd_rn(__fmul_rn(dx, dx), __fmul_rn(dy, dy)),
                           __fmul_rn(dz, dz));
      float nd = fminf(dist[j], d);
      dist[j] = nd;
      if (nd > bd) { bd = nd; bj = j; }  // ascending idx + strict > => first-max
    }
    int gi = bj * NT1 + t;
    // wave-level lexicographic (max d, tie -> min idx)
#pragma unroll
    for (int off = 1; off < 64; off <<= 1) {
      float od = __shfl_xor(bd, off);
      int   oi = __shfl_xor(gi, off);
      if (od > bd || (od == bd && oi < gi)) { bd = od; gi = oi; }
    }
    if ((t & 63) == 0) { red_d[t >> 6] = bd; red_i[t >> 6] = gi; }
    __syncthreads();
    if (t < 64) {  // parallel final reduce by wave 0 (16 partials)
      float vd = (t < 16) ? red_d[t] : -INFINITY;
      int   vi = (t < 16) ? red_i[t] : 0x7fffffff;
#pragma unroll
      for (int off = 1; off < 16; off <<= 1) {
        float od = __shfl_xor(vd, off);
        int   oi = __shfl_xor(vi, off);
        if (od > vd || (od == vd && oi < vi)) { vd = od; vi = oi; }
      }
      if (t == 0) {
        float wx = P[(size_t)vi * 3 + 0];
        float wy = P[(size_t)vi * 3 + 1];
        float wz = P[(size_t)vi * 3 + 2];
        cur[0] = wx; cur[1] = wy; cur[2] = wz;
        cent[it * 3 + 0] = wx; cent[it * 3 + 1] = wy; cent[it * 3 + 2] = wz;
      }
    }
    __syncthreads();
  }

  // morton step 1: m = argmin_{j>=1} cdist(c0, cj), ref expansion formula
  if (t < GG) {
    float c0x = cent[0], c0y = cent[1], c0z = cent[2];
    float cjx = cent[t * 3 + 0], cjy = cent[t * 3 + 1], cjz = cent[t * 3 + 2];
    float sa = sq3(c0x, c0y, c0z);
    float sb = sq3(cjx, cjy, cjz);
    float dt = dot3(c0x, c0y, c0z, cjx, cjy, cjz);
    float dd = __fsub_rn(__fadd_rn(sa, sb), __fmul_rn(2.0f, dt));
    darr[t] = (t == 0) ? INFINITY : dd;
  }
  __syncthreads();
  if (t == 0) {
    float vd = darr[1]; int vi = 1;
    for (int j = 2; j < GG; ++j) {
      float od = darr[j];
      if (od < vd) { vd = od; vi = j; }  // strict < => first-min
    }
    msh[0] = vi;
    float* gc = ws + WS_GC + b * 6;
    gc[0] = cent[0];          gc[1] = cent[1];          gc[2] = cent[2];
    gc[3] = cent[vi * 3 + 0]; gc[4] = cent[vi * 3 + 1]; gc[5] = cent[vi * 3 + 2];
  }
  __syncthreads();
  int m = msh[0];
  // centroid output: pos0 = c0, pos1 = cm, pos>=2 = c0 (morton degeneracy)
  if (t < GG * 3) {
    int pos = t / 3, c = t % 3;
    float v = (pos == 1) ? cent[m * 3 + c] : cent[c];
    out[(size_t)b * GG * 3 + t] = v;
  }
}

// ---------------------------------------------------------------------------
// Kernel 2: top-64 nearest points for centroid {0, m} of each batch.
// 32 blocks (batch x which), 64 extraction rounds, lexicographic (d, idx).
// ---------------------------------------------------------------------------
__global__ void __launch_bounds__(NT1) k_topk(const float* __restrict__ points,
                                              float* __restrict__ ws) {
  __shared__ float red_d[16];
  __shared__ int   red_i[16];
  __shared__ int   win_sh;
  __shared__ int   winners[KK];

  const int blk = blockIdx.x;
  const int b = blk >> 1, which = blk & 1;
  const int t = threadIdx.x;
  const float* P = points + (size_t)b * NN * 3;
  const float* gc = ws + WS_GC + b * 6 + which * 3;
  const float cx = gc[0], cy = gc[1], cz = gc[2];
  const float sa = sq3(cx, cy, cz);

  float darr[PPT];
#pragma unroll
  for (int j = 0; j < PPT; ++j) {
    int p = t + j * NT1;
    float px = P[p * 3 + 0], py = P[p * 3 + 1], pz = P[p * 3 + 2];
    float sb = sq3(px, py, pz);
    float dt = dot3(cx, cy, cz, px, py, pz);
    darr[j] = __fsub_rn(__fadd_rn(sa, sb), __fmul_rn(2.0f, dt));
  }
  float bd = INFINITY; int bj = 0;
#pragma unroll
  for (int j = 0; j < PPT; ++j)
    if (darr[j] < bd) { bd = darr[j]; bj = j; }

  for (int r = 0; r < KK; ++r) {
    float rd = bd; int ri = bj * NT1 + t;
#pragma unroll
    for (int off = 1; off < 64; off <<= 1) {
      float od = __shfl_xor(rd, off);
      int   oi = __shfl_xor(ri, off);
      if (od < rd || (od == rd && oi < ri)) { rd = od; ri = oi; }
    }
    if ((t & 63) == 0) { red_d[t >> 6] = rd; red_i[t >> 6] = ri; }
    __syncthreads();
    if (t == 0) {
      float vd = red_d[0]; int vi = red_i[0];
      for (int w = 1; w < NT1 / 64; ++w) {
        float od = red_d[w]; int oi = red_i[w];
        if (od < vd || (od == vd && oi < vi)) { vd = od; vi = oi; }
      }
      winners[r] = vi;
      win_sh = vi;
    }
    __syncthreads();
    int wi = win_sh;
    if (t == (wi & (NT1 - 1))) {  // owner invalidates extracted slot, rescans
      int slot = wi >> 10;
#pragma unroll
      for (int j = 0; j < PPT; ++j)
        if (j == slot) darr[j] = INFINITY;
      bd = INFINITY; bj = 0;
#pragma unroll
      for (int j = 0; j < PPT; ++j)
        if (darr[j] < bd) { bd = darr[j]; bj = j; }
    }
  }
  __syncthreads();
  if (t < KK) {  // emit local coords (order within group is irrelevant)
    int wi = winners[t];
    float px = P[(size_t)wi * 3 + 0], py = P[(size_t)wi * 3 + 1],
          pz = P[(size_t)wi * 3 + 2];
    int g = b * 2 + which;
    float* lout = ws + WS_LOCAL + (size_t)(g * KK + t) * 3;
    lout[0] = __fsub_rn(px, cx);
    lout[1] = __fsub_rn(py, cy);
    lout[2] = __fsub_rn(pz, cz);
  }
}

// ---------------------------------------------------------------------------
// Kernel 3 (stage A): f1 = relu(bn1(w1@x + b1)); f2 = w2@f1 + b2; fg = max_k f2
// One block per group (32). lane = k-point -> conflict-free LDS, scalar weights.
// ---------------------------------------------------------------------------
__global__ void __launch_bounds__(256) k_encA(
    float* __restrict__ ws,
    const float* __restrict__ w1, const float* __restrict__ b1,
    const float* __restrict__ g1, const float* __restrict__ be1,
    const float* __restrict__ m1, const float* __restrict__ v1,
    const float* __restrict__ w2, const float* __restrict__ b2) {
  __shared__ float xl[KK * 3];
  __shared__ float f1s[128 * 65];  // pad 65 to avoid bank conflicts on writes
  const int g = blockIdx.x;
  const int t = threadIdx.x;
  const float* loc = ws + WS_LOCAL + (size_t)g * KK * 3;
  if (t < KK * 3) xl[t] = loc[t];
  __syncthreads();
  {
    const int o = t & 127, kh = t >> 7;
    float wx = w1[o * 3 + 0], wy = w1[o * 3 + 1], wz = w1[o * 3 + 2];
    float inv = g1[o] * (1.0f / sqrtf(v1[o] + 1e-5f));
    float add = be1[o] - m1[o] * inv;
    float bb = b1[o];
    for (int kk = 0; kk < 32; ++kk) {
      int k = kh * 32 + kk;
      float f = fmaf(wx, xl[k * 3 + 0],
                fmaf(wy, xl[k * 3 + 1],
                fmaf(wz, xl[k * 3 + 2], bb)));
      f = fmaf(f, inv, add);
      f1s[o * 65 + k] = fmaxf(f, 0.0f);
    }
  }
  __syncthreads();
  const int k  = t & 63;
  const int og = __builtin_amdgcn_readfirstlane(t >> 6);
  const int ob = og * 64;
  float acc[64];
#pragma unroll
  for (int o = 0; o < 64; ++o) acc[o] = b2[ob + o];
  for (int i = 0; i < 128; ++i) {
    float xv = f1s[i * 65 + k];
#pragma unroll
    for (int o = 0; o < 64; ++o)
      acc[o] = fmaf(w2[(ob + o) * 128 + i], xv, acc[o]);  // uniform -> s_load
  }
  float* f2g = ws + WS_F2 + (size_t)g * 256 * 64;
#pragma unroll
  for (int o = 0; o < 64; ++o) f2g[(ob + o) * 64 + k] = acc[o];
  float* fgg = ws + WS_FG + g * 256;
#pragma unroll
  for (int o = 0; o < 64; ++o) {
    float v = acc[o];
#pragma unroll
    for (int off = 1; off < 64; off <<= 1) v = fmaxf(v, __shfl_xor(v, off));
    if (k == 0) fgg[ob + o] = v;
  }
}

// ---------------------------------------------------------------------------
// Kernel 4 (stage B): f4 = relu(bn2(w3 @ concat([fg bcast, f2]) + b3))
// grid = 32 groups x 8 o-chunks of 64.
// ---------------------------------------------------------------------------
__global__ void __launch_bounds__(256) k_encB(
    float* __restrict__ ws,
    const float* __restrict__ w3, const float* __restrict__ b3,
    const float* __restrict__ g2, const float* __restrict__ be2,
    const float* __restrict__ m2, const float* __restrict__ v2) {
  __shared__ float part[4][64];
  __shared__ float sfg[64];
  const int blk = blockIdx.x;
  const int g = blk >> 3, oc = blk & 7;
  const int t = threadIdx.x;
  const int k = t & 63;
  const int og = __builtin_amdgcn_readfirstlane(t >> 6);
  const int ob = oc * 64;
  const float* fgg = ws + WS_FG + g * 256;
  {  // k-independent part: sum_{i<256} w3[o][i] * fg[i]
    int o = ob + k;
    float s = 0.0f;
    int i0 = og * 64;
    for (int ii = 0; ii < 64; ++ii) {
      int i = i0 + ii;
      s = fmaf(w3[(size_t)o * 512 + i], fgg[i], s);
    }
    part[og][k] = s;
  }
  __syncthreads();
  if (t < 64)
    sfg[t] = b3[ob + t] + ((part[0][t] + part[1][t]) + (part[2][t] + part[3][t]));
  __syncthreads();
  const int o0 = ob + og * 16;
  float acc[16];
#pragma unroll
  for (int oo = 0; oo < 16; ++oo) acc[oo] = sfg[og * 16 + oo];
  const float* f2g = ws + WS_F2 + (size_t)g * 256 * 64;
  for (int i = 0; i < 256; ++i) {
    float xv = f2g[i * 64 + k];
#pragma unroll
    for (int oo = 0; oo < 16; ++oo)
      acc[oo] = fmaf(w3[(size_t)(o0 + oo) * 512 + 256 + i], xv, acc[oo]);
  }
  float* f4g = ws + WS_F4 + (size_t)g * 512 * 64;
#pragma unroll
  for (int oo = 0; oo < 16; ++oo) {
    int o = o0 + oo;
    float inv = g2[o] * (1.0f / sqrtf(v2[o] + 1e-5f));
    float add = be2[o] - m2[o] * inv;
    f4g[o * 64 + k] = fmaxf(fmaf(acc[oo], inv, add), 0.0f);
  }
}

// ---------------------------------------------------------------------------
// Kernel 5 (stage C): token = max_k (w4 @ f4 + b4). grid = 32 x 12 chunks of 32.
// ---------------------------------------------------------------------------
__global__ void __launch_bounds__(256) k_encC(float* __restrict__ ws,
                                              const float* __restrict__ w4,
                                              const float* __restrict__ b4) {
  const int blk = blockIdx.x;
  const int g = blk / 12, oc = blk % 12;
  const int t = threadIdx.x;
  const int k = t & 63;
  const int og = __builtin_amdgcn_readfirstlane(t >> 6);
  const int o0 = oc * 32 + og * 8;
  float acc[8];
#pragma unroll
  for (int oo = 0; oo < 8; ++oo) acc[oo] = b4[o0 + oo];
  const float* f4g = ws + WS_F4 + (size_t)g * 512 * 64;
  for (int i = 0; i < 512; ++i) {
    float xv = f4g[i * 64 + k];
#pragma unroll
    for (int oo = 0; oo < 8; ++oo)
      acc[oo] = fmaf(w4[(size_t)(o0 + oo) * 512 + i], xv, acc[oo]);
  }
  float* tokg = ws + WS_TOK + g * EDD;
#pragma unroll
  for (int oo = 0; oo < 8; ++oo) {
    float v = acc[oo];
#pragma unroll
    for (int off = 1; off < 64; off <<= 1) v = fmaxf(v, __shfl_xor(v, off));
    if (k == 0) tokg[o0 + oo] = v;
  }
}

// ---------------------------------------------------------------------------
// Kernel 6: broadcast tokens -> d_out (pos0 & pos>=2 from group0, pos1 from m).
// ---------------------------------------------------------------------------
__global__ void k_bcast(const float* __restrict__ ws, float* __restrict__ out) {
  int i = blockIdx.x * 256 + threadIdx.x;
  if (i >= BB * GG * EDD) return;
  int o = i % EDD;
  int pos = (i / EDD) % GG;
  int b = i / (EDD * GG);
  int g = b * 2 + (pos == 1 ? 1 : 0);
  out[BB * GG * 3 + i] = ws[WS_TOK + g * EDD + o];
}

extern "C" void kernel_launch(void* const* d_in, const int* in_sizes, int n_in,
                              void* d_out, int out_size, void* d_ws, size_t ws_size,
                              hipStream_t stream) {
  const float* points = (const float*)d_in[0];
  const float* w1  = (const float*)d_in[1];
  const float* b1  = (const float*)d_in[2];
  const float* g1  = (const float*)d_in[3];
  const float* be1 = (const float*)d_in[4];
  const float* m1  = (const float*)d_in[5];
  const float* v1  = (const float*)d_in[6];
  const float* w2  = (const float*)d_in[7];
  const float* b2  = (const float*)d_in[8];
  const float* w3  = (const float*)d_in[9];
  const float* b3  = (const float*)d_in[10];
  const float* g2  = (const float*)d_in[11];
  const float* be2 = (const float*)d_in[12];
  const float* m2  = (const float*)d_in[13];
  const float* v2  = (const float*)d_in[14];
  const float* w4  = (const float*)d_in[15];
  const float* b4  = (const float*)d_in[16];
  float* out = (float*)d_out;
  float* ws  = (float*)d_ws;

  // z[32768] + small scratch in dynamic LDS (>64KB needs the opt-in attr;
  // host-side call, not a stream op, safe under graph capture; idempotent)
  size_t dyn = (size_t)(NN + 640) * sizeof(float);
  hipFuncSetAttribute(reinterpret_cast<const void*>(k_fps),
                      hipFuncAttributeMaxDynamicSharedMemorySize, (int)dyn);

  hipLaunchKernelGGL(k_fps, dim3(BB), dim3(NT1), dyn, stream, points, out, ws);
  hipLaunchKernelGGL(k_topk, dim3(32), dim3(NT1), 0, stream, points, ws);
  hipLaunchKernelGGL(k_encA, dim3(32), dim3(256), 0, stream,
                     ws, w1, b1, g1, be1, m1, v1, w2, b2);
  hipLaunchKernelGGL(k_encB, dim3(256), dim3(256), 0, stream,
                     ws, w3, b3, g2, be2, m2, v2);
  hipLaunchKernelGGL(k_encC, dim3(384), dim3(256), 0, stream, ws, w4, b4);
  int tot = BB * GG * EDD;
  hipLaunchKernelGGL(k_bcast, dim3((tot + 255) / 256), dim3(256), 0, stream,
                     ws, out);
}

// Round 3
// 1467.871 us; speedup vs baseline: 1.0127x; 1.0127x over previous
//
#include <hip/hip_runtime.h>
#include <math.h>

#define BB   16
#define NN   32768
#define GG   128
#define KK   64
#define EDD  384
#define NT1  1024
#define PPT  32   // NN / NT1

// ---- workspace layout (float offsets) ----
#define WS_GC     0          // [16][2][3]      = 96     (c0, cm per batch)
#define WS_LOCAL  96         // [32][64][3]     = 6144   (local coords per group)
#define WS_F2     6240       // [32][256][64]   = 524288
#define WS_FG     530528     // [32][256]       = 8192
#define WS_F4     538720     // [32][512][64]   = 1048576
#define WS_TOK    1587296    // [32][384]       = 12288
// total = 1,599,584 floats = ~6.4 MB

__device__ __forceinline__ float sq3(float a, float b, float c) {
  // matches np: ((a*a + b*b) + c*c), no FMA contraction
  return __fadd_rn(__fadd_rn(__fmul_rn(a, a), __fmul_rn(b, b)), __fmul_rn(c, c));
}
__device__ __forceinline__ float dot3(float ax, float ay, float az,
                                      float bx, float by, float bz) {
  return __fadd_rn(__fadd_rn(__fmul_rn(ax, bx), __fmul_rn(ay, by)), __fmul_rn(az, bz));
}

// ---------------------------------------------------------------------------
// Kernel 1: FPS (127 sequential argmax rounds) + morton-m + centroid output.
// One block per batch. x/y/dist in VGPRs (96 data regs), z in LDS (128 KiB).
// amdgpu_waves_per_eu(4,4): pin occupancy target to 4 waves/EU -> VGPR budget
// 128. R2 post-mortem: __launch_bounds__(1024,4) only sets the MIN; the
// allocator still targeted 8 waves/EU (=64 VGPR) and spilled all arrays to
// scratch (VGPR_Count=64, WRITE_SIZE 3.8 MB of scratch traffic). LDS 128 KiB
// caps us at 1 block/CU = 4 waves/EU regardless, so (4,4) costs nothing.
// ---------------------------------------------------------------------------
__attribute__((amdgpu_flat_work_group_size(NT1, NT1)))
__attribute__((amdgpu_waves_per_eu(4, 4)))
__global__ void k_fps(const float* __restrict__ points,
                      float* __restrict__ out,
                      float* __restrict__ ws) {
  extern __shared__ float smem[];
  float* zsh   = smem;                       // [NN]
  float* red_d = smem + NN;                  // [16]
  int*   red_i = (int*)(smem + NN + 16);     // [16]
  float* cur   = smem + NN + 32;             // [3]
  float* cent  = smem + NN + 36;             // [GG*3]
  float* darr  = smem + NN + 420;            // [GG]
  int*   msh   = (int*)(smem + NN + 548);    // [1]

  const int b = blockIdx.x;
  const int t = threadIdx.x;
  const float* P = points + (size_t)b * NN * 3;

  float x[PPT], y[PPT], dist[PPT];
#pragma unroll
  for (int j = 0; j < PPT; ++j) {
    int p = t + j * NT1;
    x[j] = P[p * 3 + 0];
    y[j] = P[p * 3 + 1];
    zsh[p] = P[p * 3 + 2];
    dist[j] = INFINITY;
  }
  if (t == 0) {  // first centroid is point 0 (FPS init far=0)
    float z0 = P[2];
    cur[0] = x[0]; cur[1] = y[0]; cur[2] = z0;
    cent[0] = x[0]; cent[1] = y[0]; cent[2] = z0;
  }
  __syncthreads();

  for (int it = 1; it < GG; ++it) {
    float cx = cur[0], cy = cur[1], cz = cur[2];
    float bd = -1.0f; int bj = 0;
#pragma unroll
    for (int j = 0; j < PPT; ++j) {
      float dx = __fsub_rn(x[j], cx);
      float dy = __fsub_rn(y[j], cy);
      float dz = __fsub_rn(zsh[t + j * NT1], cz);
      float d  = __fadd_rn(__fadd_rn(__fmul_rn(dx, dx), __fmul_rn(dy, dy)),
                           __fmul_rn(dz, dz));
      float nd = fminf(dist[j], d);
      dist[j] = nd;
      if (nd > bd) { bd = nd; bj = j; }  // ascending idx + strict > => first-max
    }
    int gi = bj * NT1 + t;
    // wave-level lexicographic (max d, tie -> min idx)
#pragma unroll
    for (int off = 1; off < 64; off <<= 1) {
      float od = __shfl_xor(bd, off);
      int   oi = __shfl_xor(gi, off);
      if (od > bd || (od == bd && oi < gi)) { bd = od; gi = oi; }
    }
    if ((t & 63) == 0) { red_d[t >> 6] = bd; red_i[t >> 6] = gi; }
    __syncthreads();
    if (t < 64) {  // parallel final reduce by wave 0 (16 partials)
      float vd = (t < 16) ? red_d[t] : -INFINITY;
      int   vi = (t < 16) ? red_i[t] : 0x7fffffff;
#pragma unroll
      for (int off = 1; off < 16; off <<= 1) {
        float od = __shfl_xor(vd, off);
        int   oi = __shfl_xor(vi, off);
        if (od > vd || (od == vd && oi < vi)) { vd = od; vi = oi; }
      }
      if (t == 0) {
        float wx = P[(size_t)vi * 3 + 0];
        float wy = P[(size_t)vi * 3 + 1];
        float wz = P[(size_t)vi * 3 + 2];
        cur[0] = wx; cur[1] = wy; cur[2] = wz;
        cent[it * 3 + 0] = wx; cent[it * 3 + 1] = wy; cent[it * 3 + 2] = wz;
      }
    }
    __syncthreads();
  }

  // morton step 1: m = argmin_{j>=1} cdist(c0, cj), ref expansion formula
  if (t < GG) {
    float c0x = cent[0], c0y = cent[1], c0z = cent[2];
    float cjx = cent[t * 3 + 0], cjy = cent[t * 3 + 1], cjz = cent[t * 3 + 2];
    float sa = sq3(c0x, c0y, c0z);
    float sb = sq3(cjx, cjy, cjz);
    float dt = dot3(c0x, c0y, c0z, cjx, cjy, cjz);
    float dd = __fsub_rn(__fadd_rn(sa, sb), __fmul_rn(2.0f, dt));
    darr[t] = (t == 0) ? INFINITY : dd;
  }
  __syncthreads();
  if (t == 0) {
    float vd = darr[1]; int vi = 1;
    for (int j = 2; j < GG; ++j) {
      float od = darr[j];
      if (od < vd) { vd = od; vi = j; }  // strict < => first-min
    }
    msh[0] = vi;
    float* gc = ws + WS_GC + b * 6;
    gc[0] = cent[0];          gc[1] = cent[1];          gc[2] = cent[2];
    gc[3] = cent[vi * 3 + 0]; gc[4] = cent[vi * 3 + 1]; gc[5] = cent[vi * 3 + 2];
  }
  __syncthreads();
  int m = msh[0];
  // centroid output: pos0 = c0, pos1 = cm, pos>=2 = c0 (morton degeneracy)
  if (t < GG * 3) {
    int pos = t / 3, c = t % 3;
    float v = (pos == 1) ? cent[m * 3 + c] : cent[c];
    out[(size_t)b * GG * 3 + t] = v;
  }
}

// ---------------------------------------------------------------------------
// Kernel 2: top-64 nearest points for centroid {0, m} of each batch.
// 32 blocks (batch x which), 64 extraction rounds, lexicographic (d, idx).
// ---------------------------------------------------------------------------
__global__ void __launch_bounds__(NT1) k_topk(const float* __restrict__ points,
                                              float* __restrict__ ws) {
  __shared__ float red_d[16];
  __shared__ int   red_i[16];
  __shared__ int   win_sh;
  __shared__ int   winners[KK];

  const int blk = blockIdx.x;
  const int b = blk >> 1, which = blk & 1;
  const int t = threadIdx.x;
  const float* P = points + (size_t)b * NN * 3;
  const float* gc = ws + WS_GC + b * 6 + which * 3;
  const float cx = gc[0], cy = gc[1], cz = gc[2];
  const float sa = sq3(cx, cy, cz);

  float darr[PPT];
#pragma unroll
  for (int j = 0; j < PPT; ++j) {
    int p = t + j * NT1;
    float px = P[p * 3 + 0], py = P[p * 3 + 1], pz = P[p * 3 + 2];
    float sb = sq3(px, py, pz);
    float dt = dot3(cx, cy, cz, px, py, pz);
    darr[j] = __fsub_rn(__fadd_rn(sa, sb), __fmul_rn(2.0f, dt));
  }
  float bd = INFINITY; int bj = 0;
#pragma unroll
  for (int j = 0; j < PPT; ++j)
    if (darr[j] < bd) { bd = darr[j]; bj = j; }

  for (int r = 0; r < KK; ++r) {
    float rd = bd; int ri = bj * NT1 + t;
#pragma unroll
    for (int off = 1; off < 64; off <<= 1) {
      float od = __shfl_xor(rd, off);
      int   oi = __shfl_xor(ri, off);
      if (od < rd || (od == rd && oi < ri)) { rd = od; ri = oi; }
    }
    if ((t & 63) == 0) { red_d[t >> 6] = rd; red_i[t >> 6] = ri; }
    __syncthreads();
    if (t == 0) {
      float vd = red_d[0]; int vi = red_i[0];
      for (int w = 1; w < NT1 / 64; ++w) {
        float od = red_d[w]; int oi = red_i[w];
        if (od < vd || (od == vd && oi < vi)) { vd = od; vi = oi; }
      }
      winners[r] = vi;
      win_sh = vi;
    }
    __syncthreads();
    int wi = win_sh;
    if (t == (wi & (NT1 - 1))) {  // owner invalidates extracted slot, rescans
      int slot = wi >> 10;
#pragma unroll
      for (int j = 0; j < PPT; ++j)
        if (j == slot) darr[j] = INFINITY;
      bd = INFINITY; bj = 0;
#pragma unroll
      for (int j = 0; j < PPT; ++j)
        if (darr[j] < bd) { bd = darr[j]; bj = j; }
    }
  }
  __syncthreads();
  if (t < KK) {  // emit local coords (order within group is irrelevant)
    int wi = winners[t];
    float px = P[(size_t)wi * 3 + 0], py = P[(size_t)wi * 3 + 1],
          pz = P[(size_t)wi * 3 + 2];
    int g = b * 2 + which;
    float* lout = ws + WS_LOCAL + (size_t)(g * KK + t) * 3;
    lout[0] = __fsub_rn(px, cx);
    lout[1] = __fsub_rn(py, cy);
    lout[2] = __fsub_rn(pz, cz);
  }
}

// ---------------------------------------------------------------------------
// Kernel 3 (stage A): f1 = relu(bn1(w1@x + b1)); f2 = w2@f1 + b2; fg = max_k f2
// One block per group (32). lane = k-point -> conflict-free LDS, scalar weights.
// ---------------------------------------------------------------------------
__global__ void __launch_bounds__(256) k_encA(
    float* __restrict__ ws,
    const float* __restrict__ w1, const float* __restrict__ b1,
    const float* __restrict__ g1, const float* __restrict__ be1,
    const float* __restrict__ m1, const float* __restrict__ v1,
    const float* __restrict__ w2, const float* __restrict__ b2) {
  __shared__ float xl[KK * 3];
  __shared__ float f1s[128 * 65];  // pad 65 to avoid bank conflicts on writes
  const int g = blockIdx.x;
  const int t = threadIdx.x;
  const float* loc = ws + WS_LOCAL + (size_t)g * KK * 3;
  if (t < KK * 3) xl[t] = loc[t];
  __syncthreads();
  {
    const int o = t & 127, kh = t >> 7;
    float wx = w1[o * 3 + 0], wy = w1[o * 3 + 1], wz = w1[o * 3 + 2];
    float inv = g1[o] * (1.0f / sqrtf(v1[o] + 1e-5f));
    float add = be1[o] - m1[o] * inv;
    float bb = b1[o];
    for (int kk = 0; kk < 32; ++kk) {
      int k = kh * 32 + kk;
      float f = fmaf(wx, xl[k * 3 + 0],
                fmaf(wy, xl[k * 3 + 1],
                fmaf(wz, xl[k * 3 + 2], bb)));
      f = fmaf(f, inv, add);
      f1s[o * 65 + k] = fmaxf(f, 0.0f);
    }
  }
  __syncthreads();
  const int k  = t & 63;
  const int og = __builtin_amdgcn_readfirstlane(t >> 6);
  const int ob = og * 64;
  float acc[64];
#pragma unroll
  for (int o = 0; o < 64; ++o) acc[o] = b2[ob + o];
  for (int i = 0; i < 128; ++i) {
    float xv = f1s[i * 65 + k];
#pragma unroll
    for (int o = 0; o < 64; ++o)
      acc[o] = fmaf(w2[(ob + o) * 128 + i], xv, acc[o]);  // uniform -> s_load
  }
  float* f2g = ws + WS_F2 + (size_t)g * 256 * 64;
#pragma unroll
  for (int o = 0; o < 64; ++o) f2g[(ob + o) * 64 + k] = acc[o];
  float* fgg = ws + WS_FG + g * 256;
#pragma unroll
  for (int o = 0; o < 64; ++o) {
    float v = acc[o];
#pragma unroll
    for (int off = 1; off < 64; off <<= 1) v = fmaxf(v, __shfl_xor(v, off));
    if (k == 0) fgg[ob + o] = v;
  }
}

// ---------------------------------------------------------------------------
// Kernel 4 (stage B): f4 = relu(bn2(w3 @ concat([fg bcast, f2]) + b3))
// grid = 32 groups x 8 o-chunks of 64.
// ---------------------------------------------------------------------------
__global__ void __launch_bounds__(256) k_encB(
    float* __restrict__ ws,
    const float* __restrict__ w3, const float* __restrict__ b3,
    const float* __restrict__ g2, const float* __restrict__ be2,
    const float* __restrict__ m2, const float* __restrict__ v2) {
  __shared__ float part[4][64];
  __shared__ float sfg[64];
  const int blk = blockIdx.x;
  const int g = blk >> 3, oc = blk & 7;
  const int t = threadIdx.x;
  const int k = t & 63;
  const int og = __builtin_amdgcn_readfirstlane(t >> 6);
  const int ob = oc * 64;
  const float* fgg = ws + WS_FG + g * 256;
  {  // k-independent part: sum_{i<256} w3[o][i] * fg[i]
    int o = ob + k;
    float s = 0.0f;
    int i0 = og * 64;
    for (int ii = 0; ii < 64; ++ii) {
      int i = i0 + ii;
      s = fmaf(w3[(size_t)o * 512 + i], fgg[i], s);
    }
    part[og][k] = s;
  }
  __syncthreads();
  if (t < 64)
    sfg[t] = b3[ob + t] + ((part[0][t] + part[1][t]) + (part[2][t] + part[3][t]));
  __syncthreads();
  const int o0 = ob + og * 16;
  float acc[16];
#pragma unroll
  for (int oo = 0; oo < 16; ++oo) acc[oo] = sfg[og * 16 + oo];
  const float* f2g = ws + WS_F2 + (size_t)g * 256 * 64;
  for (int i = 0; i < 256; ++i) {
    float xv = f2g[i * 64 + k];
#pragma unroll
    for (int oo = 0; oo < 16; ++oo)
      acc[oo] = fmaf(w3[(size_t)(o0 + oo) * 512 + 256 + i], xv, acc[oo]);
  }
  float* f4g = ws + WS_F4 + (size_t)g * 512 * 64;
#pragma unroll
  for (int oo = 0; oo < 16; ++oo) {
    int o = o0 + oo;
    float inv = g2[o] * (1.0f / sqrtf(v2[o] + 1e-5f));
    float add = be2[o] - m2[o] * inv;
    f4g[o * 64 + k] = fmaxf(fmaf(acc[oo], inv, add), 0.0f);
  }
}

// ---------------------------------------------------------------------------
// Kernel 5 (stage C): token = max_k (w4 @ f4 + b4). grid = 32 x 12 chunks of 32.
// ---------------------------------------------------------------------------
__global__ void __launch_bounds__(256) k_encC(float* __restrict__ ws,
                                              const float* __restrict__ w4,
                                              const float* __restrict__ b4) {
  const int blk = blockIdx.x;
  const int g = blk / 12, oc = blk % 12;
  const int t = threadIdx.x;
  const int k = t & 63;
  const int og = __builtin_amdgcn_readfirstlane(t >> 6);
  const int o0 = oc * 32 + og * 8;
  float acc[8];
#pragma unroll
  for (int oo = 0; oo < 8; ++oo) acc[oo] = b4[o0 + oo];
  const float* f4g = ws + WS_F4 + (size_t)g * 512 * 64;
  for (int i = 0; i < 512; ++i) {
    float xv = f4g[i * 64 + k];
#pragma unroll
    for (int oo = 0; oo < 8; ++oo)
      acc[oo] = fmaf(w4[(size_t)(o0 + oo) * 512 + i], xv, acc[oo]);
  }
  float* tokg = ws + WS_TOK + g * EDD;
#pragma unroll
  for (int oo = 0; oo < 8; ++oo) {
    float v = acc[oo];
#pragma unroll
    for (int off = 1; off < 64; off <<= 1) v = fmaxf(v, __shfl_xor(v, off));
    if (k == 0) tokg[o0 + oo] = v;
  }
}

// ---------------------------------------------------------------------------
// Kernel 6: broadcast tokens -> d_out (pos0 & pos>=2 from group0, pos1 from m).
// ---------------------------------------------------------------------------
__global__ void k_bcast(const float* __restrict__ ws, float* __restrict__ out) {
  int i = blockIdx.x * 256 + threadIdx.x;
  if (i >= BB * GG * EDD) return;
  int o = i % EDD;
  int pos = (i / EDD) % GG;
  int b = i / (EDD * GG);
  int g = b * 2 + (pos == 1 ? 1 : 0);
  out[BB * GG * 3 + i] = ws[WS_TOK + g * EDD + o];
}

extern "C" void kernel_launch(void* const* d_in, const int* in_sizes, int n_in,
                              void* d_out, int out_size, void* d_ws, size_t ws_size,
                              hipStream_t stream) {
  const float* points = (const float*)d_in[0];
  const float* w1  = (const float*)d_in[1];
  const float* b1  = (const float*)d_in[2];
  const float* g1  = (const float*)d_in[3];
  const float* be1 = (const float*)d_in[4];
  const float* m1  = (const float*)d_in[5];
  const float* v1  = (const float*)d_in[6];
  const float* w2  = (const float*)d_in[7];
  const float* b2  = (const float*)d_in[8];
  const float* w3  = (const float*)d_in[9];
  const float* b3  = (const float*)d_in[10];
  const float* g2  = (const float*)d_in[11];
  const float* be2 = (const float*)d_in[12];
  const float* m2  = (const float*)d_in[13];
  const float* v2  = (const float*)d_in[14];
  const float* w4  = (const float*)d_in[15];
  const float* b4  = (const float*)d_in[16];
  float* out = (float*)d_out;
  float* ws  = (float*)d_ws;

  // z[32768] + small scratch in dynamic LDS (>64KB needs the opt-in attr;
  // host-side call, not a stream op, safe under graph capture; idempotent)
  size_t dyn = (size_t)(NN + 640) * sizeof(float);
  hipFuncSetAttribute(reinterpret_cast<const void*>(k_fps),
                      hipFuncAttributeMaxDynamicSharedMemorySize, (int)dyn);

  hipLaunchKernelGGL(k_fps, dim3(BB), dim3(NT1), dyn, stream, points, out, ws);
  hipLaunchKernelGGL(k_topk, dim3(32), dim3(NT1), 0, stream, points, ws);
  hipLaunchKernelGGL(k_encA, dim3(32), dim3(256), 0, stream,
                     ws, w1, b1, g1, be1, m1, v1, w2, b2);
  hipLaunchKernelGGL(k_encB, dim3(256), dim3(256), 0, stream,
                     ws, w3, b3, g2, be2, m2, v2);
  hipLaunchKernelGGL(k_encC, dim3(384), dim3(256), 0, stream, ws, w4, b4);
  int tot = BB * GG * EDD;
  hipLaunchKernelGGL(k_bcast, dim3((tot + 255) / 256), dim3(256), 0, stream,
                     ws, out);
}

// Round 4
// 1186.398 us; speedup vs baseline: 1.2529x; 1.2373x over previous
//
#include <hip/hip_runtime.h>
#include <math.h>

#define BB   16
#define NN   32768
#define GG   128
#define KK   64
#define EDD  384
#define NT1  1024
#define PPT  32   // NN / NT1

// ---- workspace layout (float offsets) ----
#define WS_GC     0          // [16][2][3]      = 96     (c0, cm per batch)
#define WS_LOCAL  96         // [32][64][3]     = 6144   (local coords per group)
#define WS_F2     6240       // [32][256][64]   = 524288
#define WS_FG     530528     // [32][256]       = 8192
#define WS_F4     538720     // [32][512][64]   = 1048576
#define WS_TOK    1587296    // [32][384]       = 12288
// total = 1,599,584 floats = ~6.4 MB

__device__ __forceinline__ float sq3(float a, float b, float c) {
  // matches np: ((a*a + b*b) + c*c), no FMA contraction
  return __fadd_rn(__fadd_rn(__fmul_rn(a, a), __fmul_rn(b, b)), __fmul_rn(c, c));
}
__device__ __forceinline__ float dot3(float ax, float ay, float az,
                                      float bx, float by, float bz) {
  return __fadd_rn(__fadd_rn(__fmul_rn(ax, bx), __fmul_rn(ay, by)), __fmul_rn(az, bz));
}

// ---------------------------------------------------------------------------
// Kernel 1: FPS (127 sequential argmax rounds) + morton-m + centroid output.
// R3 post-mortem: the compiler refuses to keep 96-float per-thread arrays in
// VGPRs (VGPR_Count pinned at 64 across launch_bounds/waves_per_eu attempts;
// arrays live in scratch -> 1 ms). New design: per-thread persistent state is
// ~15 regs; dist[32768] in LDS (thread-owned slots, conflict-free), coords
// re-streamed from global each round (L2-resident, 384 KiB/block).
// One barrier/round: parity-buffered partials + all-waves-redundant reduce.
// ---------------------------------------------------------------------------
__global__ void __launch_bounds__(NT1) k_fps(const float* __restrict__ points,
                                             float* __restrict__ out,
                                             float* __restrict__ ws) {
  extern __shared__ float smem[];
  float* dist = smem;                        // [NN]
  float* redd = smem + NN;                   // [2][16]
  int*   redi = (int*)(smem + NN + 32);      // [2][16]
  float* cent = smem + NN + 64;              // [GG*3] = 384
  float* darr = smem + NN + 448;             // [GG]
  int*   msh  = (int*)(smem + NN + 576);     // [1]

  const int b = blockIdx.x;
  const int t = threadIdx.x;
  const float* P = points + (size_t)b * NN * 3;

  // centroid 0 = point 0 (FPS init far=0); all lanes same addr -> broadcast
  float cx = P[0], cy = P[1], cz = P[2];
  if (t == 0) { cent[0] = cx; cent[1] = cy; cent[2] = cz; }
#pragma unroll
  for (int j = 0; j < PPT; ++j) dist[t + j * NT1] = INFINITY;
  // no barrier needed: dist slots are thread-owned; cent read is after the
  // loop's barriers.

  for (int it = 1; it < GG; ++it) {
    float bd = -INFINITY; int bg = 0;
#pragma unroll
    for (int j = 0; j < PPT; ++j) {
      int p = t + j * NT1;
      const float* pp = P + (size_t)p * 3;
      float px = pp[0], py = pp[1], pz = pp[2];   // -> global_load_dwordx3
      float dx = __fsub_rn(px, cx);
      float dy = __fsub_rn(py, cy);
      float dz = __fsub_rn(pz, cz);
      float d  = __fadd_rn(__fadd_rn(__fmul_rn(dx, dx), __fmul_rn(dy, dy)),
                           __fmul_rn(dz, dz));
      float nd = fminf(dist[p], d);
      dist[p] = nd;
      if (nd > bd) { bd = nd; bg = p; }  // ascending p + strict > => first-max
    }
    // wave butterfly: lexicographic (max d, tie -> min idx)
#pragma unroll
    for (int off = 1; off < 64; off <<= 1) {
      float od = __shfl_xor(bd, off);
      int   oi = __shfl_xor(bg, off);
      if (od > bd || (od == bd && oi < bg)) { bd = od; bg = oi; }
    }
    const int par = (it & 1) * 16;
    if ((t & 63) == 0) { redd[par + (t >> 6)] = bd; redi[par + (t >> 6)] = bg; }
    __syncthreads();
    // every wave redundantly reduces the 16 partials (identical result)
    {
      int l = t & 15;
      float vd = redd[par + l]; int vi = redi[par + l];
#pragma unroll
      for (int off = 1; off < 16; off <<= 1) {
        float od = __shfl_xor(vd, off);
        int   oi = __shfl_xor(vi, off);
        if (od > vd || (od == vd && oi < vi)) { vd = od; vi = oi; }
      }
      int sv = __builtin_amdgcn_readfirstlane(vi);
      const float* wp = P + (size_t)sv * 3;
      cx = wp[0]; cy = wp[1]; cz = wp[2];
      if (t == 0) { cent[it * 3 + 0] = cx; cent[it * 3 + 1] = cy; cent[it * 3 + 2] = cz; }
    }
    // parity buffers: round it+2's writes land after barrier it+1, reads of
    // round it happen before it -> no second barrier needed.
  }
  __syncthreads();  // publish cent[] to all threads

  // morton step 1: m = argmin_{j>=1} cdist(c0, cj), ref expansion formula
  if (t < GG) {
    float c0x = cent[0], c0y = cent[1], c0z = cent[2];
    float cjx = cent[t * 3 + 0], cjy = cent[t * 3 + 1], cjz = cent[t * 3 + 2];
    float sa = sq3(c0x, c0y, c0z);
    float sb = sq3(cjx, cjy, cjz);
    float dt = dot3(c0x, c0y, c0z, cjx, cjy, cjz);
    float dd = __fsub_rn(__fadd_rn(sa, sb), __fmul_rn(2.0f, dt));
    darr[t] = (t == 0) ? INFINITY : dd;
  }
  __syncthreads();
  if (t == 0) {
    float vd = darr[1]; int vi = 1;
    for (int j = 2; j < GG; ++j) {
      float od = darr[j];
      if (od < vd) { vd = od; vi = j; }  // strict < => first-min
    }
    msh[0] = vi;
    float* gc = ws + WS_GC + b * 6;
    gc[0] = cent[0];          gc[1] = cent[1];          gc[2] = cent[2];
    gc[3] = cent[vi * 3 + 0]; gc[4] = cent[vi * 3 + 1]; gc[5] = cent[vi * 3 + 2];
  }
  __syncthreads();
  int m = msh[0];
  // centroid output: pos0 = c0, pos1 = cm, pos>=2 = c0 (morton degeneracy)
  if (t < GG * 3) {
    int pos = t / 3, c = t % 3;
    float v = (pos == 1) ? cent[m * 3 + c] : cent[c];
    out[(size_t)b * GG * 3 + t] = v;
  }
}

// ---------------------------------------------------------------------------
// Kernel 2: top-64 nearest points for centroid {0, m} of each batch.
// 32 blocks (batch x which). darr in LDS (thread-owned); 64 extraction rounds
// with parity partials + all-wave reduce; winners kept in per-thread reg.
// ---------------------------------------------------------------------------
__global__ void __launch_bounds__(NT1) k_topk(const float* __restrict__ points,
                                              float* __restrict__ ws) {
  extern __shared__ float smem[];
  float* darr = smem;                        // [NN]
  float* redd = smem + NN;                   // [2][16]
  int*   redi = (int*)(smem + NN + 32);      // [2][16]

  const int blk = blockIdx.x;
  const int b = blk >> 1, which = blk & 1;
  const int t = threadIdx.x;
  const float* P = points + (size_t)b * NN * 3;
  const float* gc = ws + WS_GC + b * 6 + which * 3;
  const float cx = gc[0], cy = gc[1], cz = gc[2];
  const float sa = sq3(cx, cy, cz);

  float bd = INFINITY; int bg = 0;
#pragma unroll
  for (int j = 0; j < PPT; ++j) {
    int p = t + j * NT1;
    const float* pp = P + (size_t)p * 3;
    float px = pp[0], py = pp[1], pz = pp[2];
    float sb = sq3(px, py, pz);
    float dt = dot3(cx, cy, cz, px, py, pz);
    float d  = __fsub_rn(__fadd_rn(sa, sb), __fmul_rn(2.0f, dt));
    darr[p] = d;
    if (d < bd) { bd = d; bg = p; }  // ascending p + strict < => first-min
  }

  int my_win = 0;
  for (int r = 0; r < KK; ++r) {
    float rd = bd; int ri = bg;
#pragma unroll
    for (int off = 1; off < 64; off <<= 1) {
      float od = __shfl_xor(rd, off);
      int   oi = __shfl_xor(ri, off);
      if (od < rd || (od == rd && oi < ri)) { rd = od; ri = oi; }
    }
    const int par = (r & 1) * 16;
    if ((t & 63) == 0) { redd[par + (t >> 6)] = rd; redi[par + (t >> 6)] = ri; }
    __syncthreads();
    int l = t & 15;
    float vd = redd[par + l]; int vi = redi[par + l];
#pragma unroll
    for (int off = 1; off < 16; off <<= 1) {
      float od = __shfl_xor(vd, off);
      int   oi = __shfl_xor(vi, off);
      if (od < vd || (od == vd && oi < vi)) { vd = od; vi = oi; }
    }
    if (t == r) my_win = vi;
    if (t == (vi & (NT1 - 1))) {  // owner invalidates + rescans its 32 slots
      darr[vi] = INFINITY;
      bd = INFINITY; bg = 0;
#pragma unroll
      for (int j = 0; j < PPT; ++j) {
        int p = t + j * NT1;
        float v = darr[p];
        if (v < bd) { bd = v; bg = p; }
      }
    }
  }
  if (t < KK) {  // thread t holds round-t winner; emit local coords
    const float* pp = P + (size_t)my_win * 3;
    int g = b * 2 + which;
    float* lout = ws + WS_LOCAL + (size_t)(g * KK + t) * 3;
    lout[0] = __fsub_rn(pp[0], cx);
    lout[1] = __fsub_rn(pp[1], cy);
    lout[2] = __fsub_rn(pp[2], cz);
  }
}

// ---------------------------------------------------------------------------
// Kernel 3 (stage A): f1 = relu(bn1(w1@x + b1)); f2 = w2@f1 + b2; fg = max_k f2
// One block per group (32). R3 fix: acc[64]/thread spilled at the 64-VGPR
// budget -> 4 chunked passes of acc[16] (re-reads f1s from LDS, cheap).
// ---------------------------------------------------------------------------
__global__ void __launch_bounds__(256) k_encA(
    float* __restrict__ ws,
    const float* __restrict__ w1, const float* __restrict__ b1,
    const float* __restrict__ g1, const float* __restrict__ be1,
    const float* __restrict__ m1, const float* __restrict__ v1,
    const float* __restrict__ w2, const float* __restrict__ b2) {
  __shared__ float xl[KK * 3];
  __shared__ float f1s[128 * 65];  // pad 65: conflict-free both phases
  const int g = blockIdx.x;
  const int t = threadIdx.x;
  const float* loc = ws + WS_LOCAL + (size_t)g * KK * 3;
  if (t < KK * 3) xl[t] = loc[t];
  __syncthreads();
  {
    const int o = t & 127, kh = t >> 7;
    float wx = w1[o * 3 + 0], wy = w1[o * 3 + 1], wz = w1[o * 3 + 2];
    float inv = g1[o] * (1.0f / sqrtf(v1[o] + 1e-5f));
    float add = be1[o] - m1[o] * inv;
    float bb = b1[o];
    for (int kk = 0; kk < 32; ++kk) {
      int k = kh * 32 + kk;
      float f = fmaf(wx, xl[k * 3 + 0],
                fmaf(wy, xl[k * 3 + 1],
                fmaf(wz, xl[k * 3 + 2], bb)));
      f = fmaf(f, inv, add);
      f1s[o * 65 + k] = fmaxf(f, 0.0f);
    }
  }
  __syncthreads();
  const int k  = t & 63;
  const int og = __builtin_amdgcn_readfirstlane(t >> 6);  // wave-uniform
  float* f2g = ws + WS_F2 + (size_t)g * 256 * 64;
  float* fgg = ws + WS_FG + g * 256;
  for (int c = 0; c < 4; ++c) {
    const int o0 = c * 64 + og * 16;
    float acc[16];
#pragma unroll
    for (int oo = 0; oo < 16; ++oo) acc[oo] = b2[o0 + oo];
    for (int i = 0; i < 128; ++i) {
      float xv = f1s[i * 65 + k];
#pragma unroll
      for (int oo = 0; oo < 16; ++oo)
        acc[oo] = fmaf(w2[(o0 + oo) * 128 + i], xv, acc[oo]);  // uniform -> s_load
    }
#pragma unroll
    for (int oo = 0; oo < 16; ++oo) f2g[(o0 + oo) * 64 + k] = acc[oo];
#pragma unroll
    for (int oo = 0; oo < 16; ++oo) {
      float v = acc[oo];
#pragma unroll
      for (int off = 1; off < 64; off <<= 1) v = fmaxf(v, __shfl_xor(v, off));
      if (k == 0) fgg[o0 + oo] = v;
    }
  }
}

// ---------------------------------------------------------------------------
// Kernel 4 (stage B): f4 = relu(bn2(w3 @ concat([fg bcast, f2]) + b3))
// grid = 32 groups x 8 o-chunks of 64.
// ---------------------------------------------------------------------------
__global__ void __launch_bounds__(256) k_encB(
    float* __restrict__ ws,
    const float* __restrict__ w3, const float* __restrict__ b3,
    const float* __restrict__ g2, const float* __restrict__ be2,
    const float* __restrict__ m2, const float* __restrict__ v2) {
  __shared__ float part[4][64];
  __shared__ float sfg[64];
  const int blk = blockIdx.x;
  const int g = blk >> 3, oc = blk & 7;
  const int t = threadIdx.x;
  const int k = t & 63;
  const int og = __builtin_amdgcn_readfirstlane(t >> 6);
  const int ob = oc * 64;
  const float* fgg = ws + WS_FG + g * 256;
  {  // k-independent part: sum_{i<256} w3[o][i] * fg[i]
    int o = ob + k;
    float s = 0.0f;
    int i0 = og * 64;
    for (int ii = 0; ii < 64; ++ii) {
      int i = i0 + ii;
      s = fmaf(w3[(size_t)o * 512 + i], fgg[i], s);
    }
    part[og][k] = s;
  }
  __syncthreads();
  if (t < 64)
    sfg[t] = b3[ob + t] + ((part[0][t] + part[1][t]) + (part[2][t] + part[3][t]));
  __syncthreads();
  const int o0 = ob + og * 16;
  float acc[16];
#pragma unroll
  for (int oo = 0; oo < 16; ++oo) acc[oo] = sfg[og * 16 + oo];
  const float* f2g = ws + WS_F2 + (size_t)g * 256 * 64;
  for (int i = 0; i < 256; ++i) {
    float xv = f2g[i * 64 + k];
#pragma unroll
    for (int oo = 0; oo < 16; ++oo)
      acc[oo] = fmaf(w3[(size_t)(o0 + oo) * 512 + 256 + i], xv, acc[oo]);
  }
  float* f4g = ws + WS_F4 + (size_t)g * 512 * 64;
#pragma unroll
  for (int oo = 0; oo < 16; ++oo) {
    int o = o0 + oo;
    float inv = g2[o] * (1.0f / sqrtf(v2[o] + 1e-5f));
    float add = be2[o] - m2[o] * inv;
    f4g[o * 64 + k] = fmaxf(fmaf(acc[oo], inv, add), 0.0f);
  }
}

// ---------------------------------------------------------------------------
// Kernel 5 (stage C): token = max_k (w4 @ f4 + b4). grid = 32 x 12 chunks of 32.
// ---------------------------------------------------------------------------
__global__ void __launch_bounds__(256) k_encC(float* __restrict__ ws,
                                              const float* __restrict__ w4,
                                              const float* __restrict__ b4) {
  const int blk = blockIdx.x;
  const int g = blk / 12, oc = blk % 12;
  const int t = threadIdx.x;
  const int k = t & 63;
  const int og = __builtin_amdgcn_readfirstlane(t >> 6);
  const int o0 = oc * 32 + og * 8;
  float acc[8];
#pragma unroll
  for (int oo = 0; oo < 8; ++oo) acc[oo] = b4[o0 + oo];
  const float* f4g = ws + WS_F4 + (size_t)g * 512 * 64;
  for (int i = 0; i < 512; ++i) {
    float xv = f4g[i * 64 + k];
#pragma unroll
    for (int oo = 0; oo < 8; ++oo)
      acc[oo] = fmaf(w4[(size_t)(o0 + oo) * 512 + i], xv, acc[oo]);
  }
  float* tokg = ws + WS_TOK + g * EDD;
#pragma unroll
  for (int oo = 0; oo < 8; ++oo) {
    float v = acc[oo];
#pragma unroll
    for (int off = 1; off < 64; off <<= 1) v = fmaxf(v, __shfl_xor(v, off));
    if (k == 0) tokg[o0 + oo] = v;
  }
}

// ---------------------------------------------------------------------------
// Kernel 6: broadcast tokens -> d_out (pos0 & pos>=2 from group0, pos1 from m).
// ---------------------------------------------------------------------------
__global__ void k_bcast(const float* __restrict__ ws, float* __restrict__ out) {
  int i = blockIdx.x * 256 + threadIdx.x;
  if (i >= BB * GG * EDD) return;
  int o = i % EDD;
  int pos = (i / EDD) % GG;
  int b = i / (EDD * GG);
  int g = b * 2 + (pos == 1 ? 1 : 0);
  out[BB * GG * 3 + i] = ws[WS_TOK + g * EDD + o];
}

extern "C" void kernel_launch(void* const* d_in, const int* in_sizes, int n_in,
                              void* d_out, int out_size, void* d_ws, size_t ws_size,
                              hipStream_t stream) {
  const float* points = (const float*)d_in[0];
  const float* w1  = (const float*)d_in[1];
  const float* b1  = (const float*)d_in[2];
  const float* g1  = (const float*)d_in[3];
  const float* be1 = (const float*)d_in[4];
  const float* m1  = (const float*)d_in[5];
  const float* v1  = (const float*)d_in[6];
  const float* w2  = (const float*)d_in[7];
  const float* b2  = (const float*)d_in[8];
  const float* w3  = (const float*)d_in[9];
  const float* b3  = (const float*)d_in[10];
  const float* g2  = (const float*)d_in[11];
  const float* be2 = (const float*)d_in[12];
  const float* m2  = (const float*)d_in[13];
  const float* v2  = (const float*)d_in[14];
  const float* w4  = (const float*)d_in[15];
  const float* b4  = (const float*)d_in[16];
  float* out = (float*)d_out;
  float* ws  = (float*)d_ws;

  // dynamic LDS >64KB needs the opt-in attr (host-side, graph-safe, idempotent)
  size_t dyn_fps  = (size_t)(NN + 640) * sizeof(float);
  size_t dyn_topk = (size_t)(NN + 128) * sizeof(float);
  hipFuncSetAttribute(reinterpret_cast<const void*>(k_fps),
                      hipFuncAttributeMaxDynamicSharedMemorySize, (int)dyn_fps);
  hipFuncSetAttribute(reinterpret_cast<const void*>(k_topk),
                      hipFuncAttributeMaxDynamicSharedMemorySize, (int)dyn_topk);

  hipLaunchKernelGGL(k_fps, dim3(BB), dim3(NT1), dyn_fps, stream, points, out, ws);
  hipLaunchKernelGGL(k_topk, dim3(32), dim3(NT1), dyn_topk, stream, points, ws);
  hipLaunchKernelGGL(k_encA, dim3(32), dim3(256), 0, stream,
                     ws, w1, b1, g1, be1, m1, v1, w2, b2);
  hipLaunchKernelGGL(k_encB, dim3(256), dim3(256), 0, stream,
                     ws, w3, b3, g2, be2, m2, v2);
  hipLaunchKernelGGL(k_encC, dim3(384), dim3(256), 0, stream, ws, w4, b4);
  int tot = BB * GG * EDD;
  hipLaunchKernelGGL(k_bcast, dim3((tot + 255) / 256), dim3(256), 0, stream,
                     ws, out);
}

// Round 5
// 789.135 us; speedup vs baseline: 1.8837x; 1.5034x over previous
//
#include <hip/hip_runtime.h>
#include <math.h>

#define BB   16
#define NN   32768
#define GG   128
#define KK   64
#define EDD  384
#define NT1  1024
#define PPT  32   // NN / NT1 (k_topk)
#define SB   4    // k_fps blocks per batch
#define SP   (NN / SB)   // 8192 points per k_fps block
#define JP   (SP / NT1)  // 8 iters/thread

// ---- workspace layout (float offsets) ----
#define WS_GC     0          // [16][2][3]      = 96     (c0, cm per batch)
#define WS_LOCAL  96         // [32][64][3]     = 6144   (local coords per group)
#define WS_F2     6240       // [32][256][64]   = 524288
#define WS_FG     530528     // [32][256]       = 8192
#define WS_F4     538720     // [32][512][64]   = 1048576
#define WS_TOK    1587296    // [32][384]       = 12288
// WS_SYNC overlays WS_F2: k_fps sync slots are dead before k_encA writes F2.
#define WS_SYNC   WS_F2      // u64 [128][16][4] = 64 KB
// total = 1,599,584 floats = ~6.4 MB

__device__ __forceinline__ float sq3(float a, float b, float c) {
  // matches np: ((a*a + b*b) + c*c), no FMA contraction
  return __fadd_rn(__fadd_rn(__fmul_rn(a, a), __fmul_rn(b, b)), __fmul_rn(c, c));
}
__device__ __forceinline__ float dot3(float ax, float ay, float az,
                                      float bx, float by, float bz) {
  return __fadd_rn(__fadd_rn(__fmul_rn(ax, bx), __fmul_rn(ay, by)), __fmul_rn(az, bz));
}
__device__ __forceinline__ unsigned long long shfl_xor_u64(unsigned long long v,
                                                           int off) {
  unsigned lo = (unsigned)v, hi = (unsigned)(v >> 32);
  lo = __shfl_xor(lo, off);
  hi = __shfl_xor(hi, off);
  return ((unsigned long long)hi << 32) | lo;
}

// LDS float offsets for k_fps
#define OFF_RED  (4 * SP)        // u64[16] leader partials (byte-8-aligned)
#define OFF_WIN  (4 * SP + 32)   // u64[1] round winner
#define OFF_CENT (4 * SP + 36)   // float[GG*3]
#define OFF_DARR (4 * SP + 36 + GG * 3)
#define OFF_MSH  (OFF_DARR + GG)
#define FPS_LDS_FLOATS (OFF_MSH + 4)

// ---------------------------------------------------------------------------
// Kernel 1: FPS. R4 post-mortem: 1 block/batch re-streamed 384 KB coords from
// L2 every round (~4 us/round) -> 730 us. Now 4 blocks/batch: slice coords
// (planar) + dist both LDS-resident (128 KB), zero streaming in the loop.
// Cross-block argmax per round: packed u64 (d_bits<<32)|~idx -> plain u64 max
// = (max d, tie min idx) = np.argmax first-max rule. Publish/spin via
// agent-scope atomics on per-round ws slots (poison 0xAA.. = top bit set =
// invalid; real d>=0 -> top bit clear). 64 blocks co-resident -> no deadlock.
// ---------------------------------------------------------------------------
__global__ void __launch_bounds__(NT1) k_fps(const float* __restrict__ points,
                                             float* __restrict__ out,
                                             float* __restrict__ ws) {
  extern __shared__ float smem[];
  float* xs   = smem;            // [SP]
  float* ys   = smem + SP;       // [SP]
  float* zs   = smem + 2 * SP;   // [SP]
  float* dist = smem + 3 * SP;   // [SP]
  unsigned long long* redp = (unsigned long long*)(smem + OFF_RED);  // [16]
  unsigned long long* winp = (unsigned long long*)(smem + OFF_WIN);  // [1]
  float* cent = smem + OFF_CENT;   // [GG*3]
  float* darr = smem + OFF_DARR;   // [GG]
  int*   msh  = (int*)(smem + OFF_MSH);

  const int gb  = blockIdx.x;
  const int b   = gb >> 2, blk = gb & 3;
  const int t   = threadIdx.x;
  const float* P = points + (size_t)b * NN * 3;
  const int base = blk * SP;
  unsigned long long* slots = (unsigned long long*)(ws + WS_SYNC);

  // stage slice coords planar + init dist (thread-owned slots)
#pragma unroll
  for (int j = 0; j < JP; ++j) {
    int q = t + j * NT1;
    const float* pp = P + (size_t)(base + q) * 3;
    xs[q] = pp[0]; ys[q] = pp[1]; zs[q] = pp[2];
    dist[q] = INFINITY;
  }
  float cx = P[0], cy = P[1], cz = P[2];  // centroid 0 = point 0
  if (blk == 0 && t == 0) { cent[0] = cx; cent[1] = cy; cent[2] = cz; }
  __syncthreads();

  for (int it = 1; it < GG; ++it) {
    unsigned long long bp = 0ULL;  // identity: d=0 bits + impossible idx field
#pragma unroll
    for (int j = 0; j < JP; ++j) {
      int q = t + j * NT1;
      float dx = __fsub_rn(xs[q], cx);
      float dy = __fsub_rn(ys[q], cy);
      float dz = __fsub_rn(zs[q], cz);
      float d  = __fadd_rn(__fadd_rn(__fmul_rn(dx, dx), __fmul_rn(dy, dy)),
                           __fmul_rn(dz, dz));
      float nd = fminf(dist[q], d);
      dist[q] = nd;
      unsigned long long cand =
          ((unsigned long long)__float_as_uint(nd) << 32) |
          (unsigned)(~(base + q));
      if (cand > bp) bp = cand;
    }
    // wave butterfly (u64 max == lexicographic max-d, min-idx)
#pragma unroll
    for (int off = 1; off < 64; off <<= 1) {
      unsigned long long o = shfl_xor_u64(bp, off);
      if (o > bp) bp = o;
    }
    if ((t & 63) == 0) redp[t >> 6] = bp;
    __syncthreads();  // barrier A
    if (t < 64) {
      unsigned long long v = redp[t & 15];
#pragma unroll
      for (int off = 1; off < 16; off <<= 1) {
        unsigned long long o = shfl_xor_u64(v, off);
        if (o > v) v = o;
      }
      if (t == 0)
        __hip_atomic_store(&slots[(size_t)it * 64 + b * 4 + blk], v,
                           __ATOMIC_RELEASE, __HIP_MEMORY_SCOPE_AGENT);
      if (t < 4) {
        unsigned long long o;
        do {
          o = __hip_atomic_load(&slots[(size_t)it * 64 + b * 4 + t],
                                __ATOMIC_ACQUIRE, __HIP_MEMORY_SCOPE_AGENT);
        } while ((long long)o < 0);  // poison has top bit set; real d>=0 clear
        unsigned long long o1 = shfl_xor_u64(o, 1);
        if (o1 > o) o = o1;
        unsigned long long o2 = shfl_xor_u64(o, 2);
        if (o2 > o) o = o2;
        if (t == 0) *winp = o;
      }
    }
    __syncthreads();  // barrier B
    unsigned long long w = *winp;
    int sv = (int)(~(unsigned)(w & 0xFFFFFFFFull));
    const float* wp = P + (size_t)sv * 3;  // wave-uniform -> broadcast load
    cx = wp[0]; cy = wp[1]; cz = wp[2];
    if (blk == 0 && t == 0) {
      cent[it * 3 + 0] = cx; cent[it * 3 + 1] = cy; cent[it * 3 + 2] = cz;
    }
  }

  if (blk != 0) return;  // epilogue on block 0 of each batch only
  __syncthreads();

  // morton step 1: m = argmin_{j>=1} cdist(c0, cj), ref expansion formula
  if (t < GG) {
    float c0x = cent[0], c0y = cent[1], c0z = cent[2];
    float cjx = cent[t * 3 + 0], cjy = cent[t * 3 + 1], cjz = cent[t * 3 + 2];
    float sa = sq3(c0x, c0y, c0z);
    float sb = sq3(cjx, cjy, cjz);
    float dt = dot3(c0x, c0y, c0z, cjx, cjy, cjz);
    float dd = __fsub_rn(__fadd_rn(sa, sb), __fmul_rn(2.0f, dt));
    darr[t] = (t == 0) ? INFINITY : dd;
  }
  __syncthreads();
  if (t == 0) {
    float vd = darr[1]; int vi = 1;
    for (int j = 2; j < GG; ++j) {
      float od = darr[j];
      if (od < vd) { vd = od; vi = j; }  // strict < => first-min
    }
    msh[0] = vi;
    float* gc = ws + WS_GC + b * 6;
    gc[0] = cent[0];          gc[1] = cent[1];          gc[2] = cent[2];
    gc[3] = cent[vi * 3 + 0]; gc[4] = cent[vi * 3 + 1]; gc[5] = cent[vi * 3 + 2];
  }
  __syncthreads();
  int m = msh[0];
  // centroid output: pos0 = c0, pos1 = cm, pos>=2 = c0 (morton degeneracy)
  if (t < GG * 3) {
    int pos = t / 3, c = t % 3;
    float v = (pos == 1) ? cent[m * 3 + c] : cent[c];
    out[(size_t)b * GG * 3 + t] = v;
  }
}

// ---------------------------------------------------------------------------
// Kernel 2: top-64 nearest points for centroid {0, m} of each batch.
// 32 blocks (batch x which). darr in LDS (thread-owned); 64 extraction rounds
// with parity partials + all-wave reduce; winners kept in per-thread reg.
// ---------------------------------------------------------------------------
__global__ void __launch_bounds__(NT1) k_topk(const float* __restrict__ points,
                                              float* __restrict__ ws) {
  extern __shared__ float smem[];
  float* darr = smem;                        // [NN]
  float* redd = smem + NN;                   // [2][16]
  int*   redi = (int*)(smem + NN + 32);      // [2][16]

  const int blk = blockIdx.x;
  const int b = blk >> 1, which = blk & 1;
  const int t = threadIdx.x;
  const float* P = points + (size_t)b * NN * 3;
  const float* gc = ws + WS_GC + b * 6 + which * 3;
  const float cx = gc[0], cy = gc[1], cz = gc[2];
  const float sa = sq3(cx, cy, cz);

  float bd = INFINITY; int bg = 0;
#pragma unroll
  for (int j = 0; j < PPT; ++j) {
    int p = t + j * NT1;
    const float* pp = P + (size_t)p * 3;
    float px = pp[0], py = pp[1], pz = pp[2];
    float sb = sq3(px, py, pz);
    float dt = dot3(cx, cy, cz, px, py, pz);
    float d  = __fsub_rn(__fadd_rn(sa, sb), __fmul_rn(2.0f, dt));
    darr[p] = d;
    if (d < bd) { bd = d; bg = p; }  // ascending p + strict < => first-min
  }

  int my_win = 0;
  for (int r = 0; r < KK; ++r) {
    float rd = bd; int ri = bg;
#pragma unroll
    for (int off = 1; off < 64; off <<= 1) {
      float od = __shfl_xor(rd, off);
      int   oi = __shfl_xor(ri, off);
      if (od < rd || (od == rd && oi < ri)) { rd = od; ri = oi; }
    }
    const int par = (r & 1) * 16;
    if ((t & 63) == 0) { redd[par + (t >> 6)] = rd; redi[par + (t >> 6)] = ri; }
    __syncthreads();
    int l = t & 15;
    float vd = redd[par + l]; int vi = redi[par + l];
#pragma unroll
    for (int off = 1; off < 16; off <<= 1) {
      float od = __shfl_xor(vd, off);
      int   oi = __shfl_xor(vi, off);
      if (od < vd || (od == vd && oi < vi)) { vd = od; vi = oi; }
    }
    if (t == r) my_win = vi;
    if (t == (vi & (NT1 - 1))) {  // owner invalidates + rescans its 32 slots
      darr[vi] = INFINITY;
      bd = INFINITY; bg = 0;
#pragma unroll
      for (int j = 0; j < PPT; ++j) {
        int p = t + j * NT1;
        float v = darr[p];
        if (v < bd) { bd = v; bg = p; }
      }
    }
  }
  if (t < KK) {  // thread t holds round-t winner; emit local coords
    const float* pp = P + (size_t)my_win * 3;
    int g = b * 2 + which;
    float* lout = ws + WS_LOCAL + (size_t)(g * KK + t) * 3;
    lout[0] = __fsub_rn(pp[0], cx);
    lout[1] = __fsub_rn(pp[1], cy);
    lout[2] = __fsub_rn(pp[2], cz);
  }
}

// ---------------------------------------------------------------------------
// Kernel 3 (stage A): f1 = relu(bn1(w1@x + b1)); f2 = w2@f1 + b2; fg = max_k f2
// One block per group (32). acc[16] chunks to stay within 64-VGPR budget.
// ---------------------------------------------------------------------------
__global__ void __launch_bounds__(256) k_encA(
    float* __restrict__ ws,
    const float* __restrict__ w1, const float* __restrict__ b1,
    const float* __restrict__ g1, const float* __restrict__ be1,
    const float* __restrict__ m1, const float* __restrict__ v1,
    const float* __restrict__ w2, const float* __restrict__ b2) {
  __shared__ float xl[KK * 3];
  __shared__ float f1s[128 * 65];  // pad 65: conflict-free both phases
  const int g = blockIdx.x;
  const int t = threadIdx.x;
  const float* loc = ws + WS_LOCAL + (size_t)g * KK * 3;
  if (t < KK * 3) xl[t] = loc[t];
  __syncthreads();
  {
    const int o = t & 127, kh = t >> 7;
    float wx = w1[o * 3 + 0], wy = w1[o * 3 + 1], wz = w1[o * 3 + 2];
    float inv = g1[o] * (1.0f / sqrtf(v1[o] + 1e-5f));
    float add = be1[o] - m1[o] * inv;
    float bb = b1[o];
    for (int kk = 0; kk < 32; ++kk) {
      int k = kh * 32 + kk;
      float f = fmaf(wx, xl[k * 3 + 0],
                fmaf(wy, xl[k * 3 + 1],
                fmaf(wz, xl[k * 3 + 2], bb)));
      f = fmaf(f, inv, add);
      f1s[o * 65 + k] = fmaxf(f, 0.0f);
    }
  }
  __syncthreads();
  const int k  = t & 63;
  const int og = __builtin_amdgcn_readfirstlane(t >> 6);  // wave-uniform
  float* f2g = ws + WS_F2 + (size_t)g * 256 * 64;
  float* fgg = ws + WS_FG + g * 256;
  for (int c = 0; c < 4; ++c) {
    const int o0 = c * 64 + og * 16;
    float acc[16];
#pragma unroll
    for (int oo = 0; oo < 16; ++oo) acc[oo] = b2[o0 + oo];
    for (int i = 0; i < 128; ++i) {
      float xv = f1s[i * 65 + k];
#pragma unroll
      for (int oo = 0; oo < 16; ++oo)
        acc[oo] = fmaf(w2[(o0 + oo) * 128 + i], xv, acc[oo]);  // uniform -> s_load
    }
#pragma unroll
    for (int oo = 0; oo < 16; ++oo) f2g[(o0 + oo) * 64 + k] = acc[oo];
#pragma unroll
    for (int oo = 0; oo < 16; ++oo) {
      float v = acc[oo];
#pragma unroll
      for (int off = 1; off < 64; off <<= 1) v = fmaxf(v, __shfl_xor(v, off));
      if (k == 0) fgg[o0 + oo] = v;
    }
  }
}

// ---------------------------------------------------------------------------
// Kernel 4 (stage B): f4 = relu(bn2(w3 @ concat([fg bcast, f2]) + b3))
// grid = 32 groups x 8 o-chunks of 64.
// ---------------------------------------------------------------------------
__global__ void __launch_bounds__(256) k_encB(
    float* __restrict__ ws,
    const float* __restrict__ w3, const float* __restrict__ b3,
    const float* __restrict__ g2, const float* __restrict__ be2,
    const float* __restrict__ m2, const float* __restrict__ v2) {
  __shared__ float part[4][64];
  __shared__ float sfg[64];
  const int blk = blockIdx.x;
  const int g = blk >> 3, oc = blk & 7;
  const int t = threadIdx.x;
  const int k = t & 63;
  const int og = __builtin_amdgcn_readfirstlane(t >> 6);
  const int ob = oc * 64;
  const float* fgg = ws + WS_FG + g * 256;
  {  // k-independent part: sum_{i<256} w3[o][i] * fg[i]
    int o = ob + k;
    float s = 0.0f;
    int i0 = og * 64;
    for (int ii = 0; ii < 64; ++ii) {
      int i = i0 + ii;
      s = fmaf(w3[(size_t)o * 512 + i], fgg[i], s);
    }
    part[og][k] = s;
  }
  __syncthreads();
  if (t < 64)
    sfg[t] = b3[ob + t] + ((part[0][t] + part[1][t]) + (part[2][t] + part[3][t]));
  __syncthreads();
  const int o0 = ob + og * 16;
  float acc[16];
#pragma unroll
  for (int oo = 0; oo < 16; ++oo) acc[oo] = sfg[og * 16 + oo];
  const float* f2g = ws + WS_F2 + (size_t)g * 256 * 64;
  for (int i = 0; i < 256; ++i) {
    float xv = f2g[i * 64 + k];
#pragma unroll
    for (int oo = 0; oo < 16; ++oo)
      acc[oo] = fmaf(w3[(size_t)(o0 + oo) * 512 + 256 + i], xv, acc[oo]);
  }
  float* f4g = ws + WS_F4 + (size_t)g * 512 * 64;
#pragma unroll
  for (int oo = 0; oo < 16; ++oo) {
    int o = o0 + oo;
    float inv = g2[o] * (1.0f / sqrtf(v2[o] + 1e-5f));
    float add = be2[o] - m2[o] * inv;
    f4g[o * 64 + k] = fmaxf(fmaf(acc[oo], inv, add), 0.0f);
  }
}

// ---------------------------------------------------------------------------
// Kernel 5 (stage C): token = max_k (w4 @ f4 + b4). grid = 32 x 12 chunks of 32.
// ---------------------------------------------------------------------------
__global__ void __launch_bounds__(256) k_encC(float* __restrict__ ws,
                                              const float* __restrict__ w4,
                                              const float* __restrict__ b4) {
  const int blk = blockIdx.x;
  const int g = blk / 12, oc = blk % 12;
  const int t = threadIdx.x;
  const int k = t & 63;
  const int og = __builtin_amdgcn_readfirstlane(t >> 6);
  const int o0 = oc * 32 + og * 8;
  float acc[8];
#pragma unroll
  for (int oo = 0; oo < 8; ++oo) acc[oo] = b4[o0 + oo];
  const float* f4g = ws + WS_F4 + (size_t)g * 512 * 64;
  for (int i = 0; i < 512; ++i) {
    float xv = f4g[i * 64 + k];
#pragma unroll
    for (int oo = 0; oo < 8; ++oo)
      acc[oo] = fmaf(w4[(size_t)(o0 + oo) * 512 + i], xv, acc[oo]);
  }
  float* tokg = ws + WS_TOK + g * EDD;
#pragma unroll
  for (int oo = 0; oo < 8; ++oo) {
    float v = acc[oo];
#pragma unroll
    for (int off = 1; off < 64; off <<= 1) v = fmaxf(v, __shfl_xor(v, off));
    if (k == 0) tokg[o0 + oo] = v;
  }
}

// ---------------------------------------------------------------------------
// Kernel 6: broadcast tokens -> d_out (pos0 & pos>=2 from group0, pos1 from m).
// ---------------------------------------------------------------------------
__global__ void k_bcast(const float* __restrict__ ws, float* __restrict__ out) {
  int i = blockIdx.x * 256 + threadIdx.x;
  if (i >= BB * GG * EDD) return;
  int o = i % EDD;
  int pos = (i / EDD) % GG;
  int b = i / (EDD * GG);
  int g = b * 2 + (pos == 1 ? 1 : 0);
  out[BB * GG * 3 + i] = ws[WS_TOK + g * EDD + o];
}

extern "C" void kernel_launch(void* const* d_in, const int* in_sizes, int n_in,
                              void* d_out, int out_size, void* d_ws, size_t ws_size,
                              hipStream_t stream) {
  const float* points = (const float*)d_in[0];
  const float* w1  = (const float*)d_in[1];
  const float* b1  = (const float*)d_in[2];
  const float* g1  = (const float*)d_in[3];
  const float* be1 = (const float*)d_in[4];
  const float* m1  = (const float*)d_in[5];
  const float* v1  = (const float*)d_in[6];
  const float* w2  = (const float*)d_in[7];
  const float* b2  = (const float*)d_in[8];
  const float* w3  = (const float*)d_in[9];
  const float* b3  = (const float*)d_in[10];
  const float* g2  = (const float*)d_in[11];
  const float* be2 = (const float*)d_in[12];
  const float* m2  = (const float*)d_in[13];
  const float* v2  = (const float*)d_in[14];
  const float* w4  = (const float*)d_in[15];
  const float* b4  = (const float*)d_in[16];
  float* out = (float*)d_out;
  float* ws  = (float*)d_ws;

  // dynamic LDS >64KB needs the opt-in attr (host-side, graph-safe, idempotent)
  size_t dyn_fps  = (size_t)FPS_LDS_FLOATS * sizeof(float);
  size_t dyn_topk = (size_t)(NN + 128) * sizeof(float);
  hipFuncSetAttribute(reinterpret_cast<const void*>(k_fps),
                      hipFuncAttributeMaxDynamicSharedMemorySize, (int)dyn_fps);
  hipFuncSetAttribute(reinterpret_cast<const void*>(k_topk),
                      hipFuncAttributeMaxDynamicSharedMemorySize, (int)dyn_topk);

  // invalidate k_fps sync slots (0xAA pattern = top bit set = invalid);
  // hipMemsetAsync is stream-ordered and graph-capture safe.
  hipMemsetAsync(ws + WS_SYNC, 0xAA, (size_t)128 * 16 * 4 * 8, stream);

  hipLaunchKernelGGL(k_fps, dim3(BB * SB), dim3(NT1), dyn_fps, stream,
                     points, out, ws);
  hipLaunchKernelGGL(k_topk, dim3(32), dim3(NT1), dyn_topk, stream, points, ws);
  hipLaunchKernelGGL(k_encA, dim3(32), dim3(256), 0, stream,
                     ws, w1, b1, g1, be1, m1, v1, w2, b2);
  hipLaunchKernelGGL(k_encB, dim3(256), dim3(256), 0, stream,
                     ws, w3, b3, g2, be2, m2, v2);
  hipLaunchKernelGGL(k_encC, dim3(384), dim3(256), 0, stream, ws, w4, b4);
  int tot = BB * GG * EDD;
  hipLaunchKernelGGL(k_bcast, dim3((tot + 255) / 256), dim3(256), 0, stream,
                     ws, out);
}

// Round 6
// 627.963 us; speedup vs baseline: 2.3671x; 1.2567x over previous
//
#include <hip/hip_runtime.h>
#include <math.h>

#define BB   16
#define NN   32768
#define GG   128
#define KK   64
#define EDD  384
#define NT1  1024
#define PPT  32   // NN / NT1 (k_grp topk phase)
#define SB   4    // k_fps blocks per batch
#define SP   (NN / SB)   // 8192 points per k_fps block
#define JP   (SP / NT1)  // 8 iters/thread

// ---- workspace layout (float offsets) ----
#define WS_GC     0          // [16][2][3]      = 96     (c0, cm per batch)
#define WS_F2     6240       // [32][256][64]   = 524288
#define WS_FG     530528     // [32][256]       = 8192
#define WS_F4     538720     // [32][512][64]   = 1048576
#define WS_SYNC   1587296    // u64 [128][16][4] = 64 KB (dedicated, no overlay)

__device__ __forceinline__ float sq3(float a, float b, float c) {
  // matches np: ((a*a + b*b) + c*c), no FMA contraction
  return __fadd_rn(__fadd_rn(__fmul_rn(a, a), __fmul_rn(b, b)), __fmul_rn(c, c));
}
__device__ __forceinline__ float dot3(float ax, float ay, float az,
                                      float bx, float by, float bz) {
  return __fadd_rn(__fadd_rn(__fmul_rn(ax, bx), __fmul_rn(ay, by)), __fmul_rn(az, bz));
}
__device__ __forceinline__ unsigned long long shfl_xor_u64(unsigned long long v,
                                                           int off) {
  unsigned lo = (unsigned)v, hi = (unsigned)(v >> 32);
  lo = __shfl_xor(lo, off);
  hi = __shfl_xor(hi, off);
  return ((unsigned long long)hi << 32) | lo;
}

// LDS float offsets for k_fps
#define OFF_RED  (4 * SP)        // u64[16] leader partials (byte-8-aligned)
#define OFF_WIN  (4 * SP + 32)   // u64[1] round winner
#define OFF_CENT (4 * SP + 36)   // float[GG*3]
#define OFF_DARR (4 * SP + 36 + GG * 3)
#define OFF_MSH  (OFF_DARR + GG)
#define FPS_LDS_FLOATS (OFF_MSH + 4)

// ---------------------------------------------------------------------------
// Kernel 1: FPS. 4 blocks/batch; slice coords (planar) + dist LDS-resident.
// Cross-block argmax per round: packed u64 (d_bits<<32)|~idx -> plain u64 max
// = (max d, tie min idx) = np.argmax first-max rule. Publish/spin via
// agent-scope atomics on per-round ws slots (poison 0xAA.. = top bit set =
// invalid; real d>=0 -> top bit clear). 64 blocks co-resident -> no deadlock.
// Measured R5: 337 us, VGPR=32, ~2.65 us/round (sync-latency bound).
// ---------------------------------------------------------------------------
__global__ void __launch_bounds__(NT1) k_fps(const float* __restrict__ points,
                                             float* __restrict__ out,
                                             float* __restrict__ ws) {
  extern __shared__ float smem[];
  float* xs   = smem;            // [SP]
  float* ys   = smem + SP;       // [SP]
  float* zs   = smem + 2 * SP;   // [SP]
  float* dist = smem + 3 * SP;   // [SP]
  unsigned long long* redp = (unsigned long long*)(smem + OFF_RED);  // [16]
  unsigned long long* winp = (unsigned long long*)(smem + OFF_WIN);  // [1]
  float* cent = smem + OFF_CENT;   // [GG*3]
  float* darr = smem + OFF_DARR;   // [GG]
  int*   msh  = (int*)(smem + OFF_MSH);

  const int gb  = blockIdx.x;
  const int b   = gb >> 2, blk = gb & 3;
  const int t   = threadIdx.x;
  const float* P = points + (size_t)b * NN * 3;
  const int base = blk * SP;
  unsigned long long* slots = (unsigned long long*)(ws + WS_SYNC);

  // stage slice coords planar + init dist (thread-owned slots)
#pragma unroll
  for (int j = 0; j < JP; ++j) {
    int q = t + j * NT1;
    const float* pp = P + (size_t)(base + q) * 3;
    xs[q] = pp[0]; ys[q] = pp[1]; zs[q] = pp[2];
    dist[q] = INFINITY;
  }
  float cx = P[0], cy = P[1], cz = P[2];  // centroid 0 = point 0
  if (blk == 0 && t == 0) { cent[0] = cx; cent[1] = cy; cent[2] = cz; }
  __syncthreads();

  for (int it = 1; it < GG; ++it) {
    unsigned long long bp = 0ULL;
#pragma unroll
    for (int j = 0; j < JP; ++j) {
      int q = t + j * NT1;
      float dx = __fsub_rn(xs[q], cx);
      float dy = __fsub_rn(ys[q], cy);
      float dz = __fsub_rn(zs[q], cz);
      float d  = __fadd_rn(__fadd_rn(__fmul_rn(dx, dx), __fmul_rn(dy, dy)),
                           __fmul_rn(dz, dz));
      float nd = fminf(dist[q], d);
      dist[q] = nd;
      unsigned long long cand =
          ((unsigned long long)__float_as_uint(nd) << 32) |
          (unsigned)(~(base + q));
      if (cand > bp) bp = cand;
    }
#pragma unroll
    for (int off = 1; off < 64; off <<= 1) {
      unsigned long long o = shfl_xor_u64(bp, off);
      if (o > bp) bp = o;
    }
    if ((t & 63) == 0) redp[t >> 6] = bp;
    __syncthreads();  // barrier A
    if (t < 64) {
      unsigned long long v = redp[t & 15];
#pragma unroll
      for (int off = 1; off < 16; off <<= 1) {
        unsigned long long o = shfl_xor_u64(v, off);
        if (o > v) v = o;
      }
      if (t == 0)
        __hip_atomic_store(&slots[(size_t)it * 64 + b * 4 + blk], v,
                           __ATOMIC_RELEASE, __HIP_MEMORY_SCOPE_AGENT);
      if (t < 4) {
        unsigned long long o;
        do {
          o = __hip_atomic_load(&slots[(size_t)it * 64 + b * 4 + t],
                                __ATOMIC_ACQUIRE, __HIP_MEMORY_SCOPE_AGENT);
        } while ((long long)o < 0);  // poison top bit set; real d>=0 clear
        unsigned long long o1 = shfl_xor_u64(o, 1);
        if (o1 > o) o = o1;
        unsigned long long o2 = shfl_xor_u64(o, 2);
        if (o2 > o) o = o2;
        if (t == 0) *winp = o;
      }
    }
    __syncthreads();  // barrier B
    unsigned long long w = *winp;
    int sv = (int)(~(unsigned)(w & 0xFFFFFFFFull));
    const float* wp = P + (size_t)sv * 3;  // wave-uniform -> broadcast load
    cx = wp[0]; cy = wp[1]; cz = wp[2];
    if (blk == 0 && t == 0) {
      cent[it * 3 + 0] = cx; cent[it * 3 + 1] = cy; cent[it * 3 + 2] = cz;
    }
  }

  if (blk != 0) return;  // epilogue on block 0 of each batch only
  __syncthreads();

  // morton step 1: m = argmin_{j>=1} cdist(c0, cj), ref expansion formula
  if (t < GG) {
    float c0x = cent[0], c0y = cent[1], c0z = cent[2];
    float cjx = cent[t * 3 + 0], cjy = cent[t * 3 + 1], cjz = cent[t * 3 + 2];
    float sa = sq3(c0x, c0y, c0z);
    float sb = sq3(cjx, cjy, cjz);
    float dt = dot3(c0x, c0y, c0z, cjx, cjy, cjz);
    float dd = __fsub_rn(__fadd_rn(sa, sb), __fmul_rn(2.0f, dt));
    darr[t] = (t == 0) ? INFINITY : dd;
  }
  __syncthreads();
  if (t == 0) {
    float vd = darr[1]; int vi = 1;
    for (int j = 2; j < GG; ++j) {
      float od = darr[j];
      if (od < vd) { vd = od; vi = j; }  // strict < => first-min
    }
    msh[0] = vi;
    float* gc = ws + WS_GC + b * 6;
    gc[0] = cent[0];          gc[1] = cent[1];          gc[2] = cent[2];
    gc[3] = cent[vi * 3 + 0]; gc[4] = cent[vi * 3 + 1]; gc[5] = cent[vi * 3 + 2];
  }
  __syncthreads();
  int m = msh[0];
  // centroid output: pos0 = c0, pos1 = cm, pos>=2 = c0 (morton degeneracy)
  if (t < GG * 3) {
    int pos = t / 3, c = t % 3;
    float v = (pos == 1) ? cent[m * 3 + c] : cent[c];
    out[(size_t)b * GG * 3 + t] = v;
  }
}

// ---------------------------------------------------------------------------
// Kernel 2 (fused topk + encA): per group (32 blocks x 1024 threads):
// top-64 extraction into LDS xl, then f1 = relu(bn1(w1@x+b1)),
// f2 = w2@f1 + b2 -> global, fg = max_k f2 -> global.
// f1s overlays the dead darr region after a barrier.
// ---------------------------------------------------------------------------
__global__ void __launch_bounds__(NT1) k_grp(
    const float* __restrict__ points, float* __restrict__ ws,
    const float* __restrict__ w1, const float* __restrict__ b1,
    const float* __restrict__ g1, const float* __restrict__ be1,
    const float* __restrict__ m1, const float* __restrict__ v1,
    const float* __restrict__ w2, const float* __restrict__ b2) {
  extern __shared__ float smem[];
  float* darr = smem;                        // [NN] (topk) / f1s overlay (encA)
  float* f1s  = smem;                        // [128*65] = 8320 <= NN
  float* redd = smem + NN;                   // [2][16]
  int*   redi = (int*)(smem + NN + 32);      // [2][16]
  float* xl   = smem + NN + 64;              // [KK*3]

  const int g = blockIdx.x;
  const int b = g >> 1, which = g & 1;
  const int t = threadIdx.x;
  const float* P = points + (size_t)b * NN * 3;
  const float* gc = ws + WS_GC + b * 6 + which * 3;
  const float cx = gc[0], cy = gc[1], cz = gc[2];
  const float sa = sq3(cx, cy, cz);

  // ---- phase 1: top-64 extraction ----
  float bd = INFINITY; int bg = 0;
#pragma unroll
  for (int j = 0; j < PPT; ++j) {
    int p = t + j * NT1;
    const float* pp = P + (size_t)p * 3;
    float px = pp[0], py = pp[1], pz = pp[2];
    float sb = sq3(px, py, pz);
    float dt = dot3(cx, cy, cz, px, py, pz);
    float d  = __fsub_rn(__fadd_rn(sa, sb), __fmul_rn(2.0f, dt));
    darr[p] = d;
    if (d < bd) { bd = d; bg = p; }  // ascending p + strict < => first-min
  }
  int my_win = 0;
  for (int r = 0; r < KK; ++r) {
    float rd = bd; int ri = bg;
#pragma unroll
    for (int off = 1; off < 64; off <<= 1) {
      float od = __shfl_xor(rd, off);
      int   oi = __shfl_xor(ri, off);
      if (od < rd || (od == rd && oi < ri)) { rd = od; ri = oi; }
    }
    const int par = (r & 1) * 16;
    if ((t & 63) == 0) { redd[par + (t >> 6)] = rd; redi[par + (t >> 6)] = ri; }
    __syncthreads();
    int l = t & 15;
    float vd = redd[par + l]; int vi = redi[par + l];
#pragma unroll
    for (int off = 1; off < 16; off <<= 1) {
      float od = __shfl_xor(vd, off);
      int   oi = __shfl_xor(vi, off);
      if (od < vd || (od == vd && oi < vi)) { vd = od; vi = oi; }
    }
    if (t == r) my_win = vi;
    if (t == (vi & (NT1 - 1))) {  // owner invalidates + rescans its 32 slots
      darr[vi] = INFINITY;
      bd = INFINITY; bg = 0;
#pragma unroll
      for (int j = 0; j < PPT; ++j) {
        int p = t + j * NT1;
        float v = darr[p];
        if (v < bd) { bd = v; bg = p; }
      }
    }
  }
  __syncthreads();  // darr dead after this point
  if (t < KK) {     // thread t holds round-t winner; local coords into LDS
    const float* pp = P + (size_t)my_win * 3;
    xl[t * 3 + 0] = __fsub_rn(pp[0], cx);
    xl[t * 3 + 1] = __fsub_rn(pp[1], cy);
    xl[t * 3 + 2] = __fsub_rn(pp[2], cz);
  }
  __syncthreads();

  // ---- phase 2: f1 = relu(bn1(w1@x + b1)) -> f1s[128][65] ----
  {
    const int o = t & 127, kh = t >> 7;  // kh in [0,8)
    float wx = w1[o * 3 + 0], wy = w1[o * 3 + 1], wz = w1[o * 3 + 2];
    float inv = g1[o] * (1.0f / sqrtf(v1[o] + 1e-5f));
    float add = be1[o] - m1[o] * inv;
    float bb = b1[o];
#pragma unroll
    for (int kk = 0; kk < 8; ++kk) {
      int k = kh * 8 + kk;
      float f = fmaf(wx, xl[k * 3 + 0],
                fmaf(wy, xl[k * 3 + 1],
                fmaf(wz, xl[k * 3 + 2], bb)));
      f = fmaf(f, inv, add);
      f1s[o * 65 + k] = fmaxf(f, 0.0f);
    }
  }
  __syncthreads();

  // ---- phase 3: f2 = w2@f1 + b2 -> global; fg = max_k -> global ----
  const int k  = t & 63;
  const int og = __builtin_amdgcn_readfirstlane(t >> 6);  // wave-uniform [0,16)
  const int o0 = og * 16;
  float acc[16];
#pragma unroll
  for (int oo = 0; oo < 16; ++oo) acc[oo] = b2[o0 + oo];
  for (int i = 0; i < 128; ++i) {
    float xv = f1s[i * 65 + k];
#pragma unroll
    for (int oo = 0; oo < 16; ++oo)
      acc[oo] = fmaf(w2[(o0 + oo) * 128 + i], xv, acc[oo]);  // uniform -> s_load
  }
  float* f2g = ws + WS_F2 + (size_t)g * 256 * 64;
  float* fgg = ws + WS_FG + g * 256;
#pragma unroll
  for (int oo = 0; oo < 16; ++oo) f2g[(o0 + oo) * 64 + k] = acc[oo];
#pragma unroll
  for (int oo = 0; oo < 16; ++oo) {
    float v = acc[oo];
#pragma unroll
    for (int off = 1; off < 64; off <<= 1) v = fmaxf(v, __shfl_xor(v, off));
    if (k == 0) fgg[o0 + oo] = v;
  }
}

// ---------------------------------------------------------------------------
// Kernel 3 (stage B): f4 = relu(bn2(w3 @ concat([fg bcast, f2]) + b3))
// grid = 32 groups x 8 o-chunks of 64.
// ---------------------------------------------------------------------------
__global__ void __launch_bounds__(256) k_encB(
    float* __restrict__ ws,
    const float* __restrict__ w3, const float* __restrict__ b3,
    const float* __restrict__ g2, const float* __restrict__ be2,
    const float* __restrict__ m2, const float* __restrict__ v2) {
  __shared__ float part[4][64];
  __shared__ float sfg[64];
  const int blk = blockIdx.x;
  const int g = blk >> 3, oc = blk & 7;
  const int t = threadIdx.x;
  const int k = t & 63;
  const int og = __builtin_amdgcn_readfirstlane(t >> 6);
  const int ob = oc * 64;
  const float* fgg = ws + WS_FG + g * 256;
  {  // k-independent part: sum_{i<256} w3[o][i] * fg[i]
    int o = ob + k;
    float s = 0.0f;
    int i0 = og * 64;
    for (int ii = 0; ii < 64; ++ii) {
      int i = i0 + ii;
      s = fmaf(w3[(size_t)o * 512 + i], fgg[i], s);
    }
    part[og][k] = s;
  }
  __syncthreads();
  if (t < 64)
    sfg[t] = b3[ob + t] + ((part[0][t] + part[1][t]) + (part[2][t] + part[3][t]));
  __syncthreads();
  const int o0 = ob + og * 16;
  float acc[16];
#pragma unroll
  for (int oo = 0; oo < 16; ++oo) acc[oo] = sfg[og * 16 + oo];
  const float* f2g = ws + WS_F2 + (size_t)g * 256 * 64;
#pragma unroll 4
  for (int i = 0; i < 256; ++i) {
    float xv = f2g[i * 64 + k];
#pragma unroll
    for (int oo = 0; oo < 16; ++oo)
      acc[oo] = fmaf(w3[(size_t)(o0 + oo) * 512 + 256 + i], xv, acc[oo]);
  }
  float* f4g = ws + WS_F4 + (size_t)g * 512 * 64;
#pragma unroll
  for (int oo = 0; oo < 16; ++oo) {
    int o = o0 + oo;
    float inv = g2[o] * (1.0f / sqrtf(v2[o] + 1e-5f));
    float add = be2[o] - m2[o] * inv;
    f4g[o * 64 + k] = fmaxf(fmaf(acc[oo], inv, add), 0.0f);
  }
}

// ---------------------------------------------------------------------------
// Kernel 4 (fused stage C + broadcast): token = max_k (w4 @ f4 + b4), written
// directly to all output positions (xor butterfly leaves max in ALL lanes;
// lanes scatter positions). grid = 32 x 12 chunks of 32.
// ---------------------------------------------------------------------------
__global__ void __launch_bounds__(256) k_encCb(float* __restrict__ ws,
                                               const float* __restrict__ w4,
                                               const float* __restrict__ b4,
                                               float* __restrict__ out) {
  const int blk = blockIdx.x;
  const int g = blk / 12, oc = blk % 12;
  const int b = g >> 1, which = g & 1;
  const int t = threadIdx.x;
  const int k = t & 63;
  const int og = __builtin_amdgcn_readfirstlane(t >> 6);
  const int o0 = oc * 32 + og * 8;
  float acc[8];
#pragma unroll
  for (int oo = 0; oo < 8; ++oo) acc[oo] = b4[o0 + oo];
  const float* f4g = ws + WS_F4 + (size_t)g * 512 * 64;
#pragma unroll 8
  for (int i = 0; i < 512; ++i) {
    float xv = f4g[i * 64 + k];
#pragma unroll
    for (int oo = 0; oo < 8; ++oo)
      acc[oo] = fmaf(w4[(size_t)(o0 + oo) * 512 + i], xv, acc[oo]);
  }
#pragma unroll
  for (int oo = 0; oo < 8; ++oo) {
#pragma unroll
    for (int off = 1; off < 64; off <<= 1)
      acc[oo] = fmaxf(acc[oo], __shfl_xor(acc[oo], off));
  }
  // all lanes now hold the per-oo max; scatter to output positions
  float* tok = out + (size_t)BB * GG * 3;
  if (which == 1) {
    if (k == 0) {
      float* dst = tok + ((size_t)b * GG + 1) * EDD + o0;
#pragma unroll
      for (int oo = 0; oo < 8; ++oo) dst[oo] = acc[oo];
    }
  } else {
#pragma unroll
    for (int rep = 0; rep < 2; ++rep) {
      int pos = k + rep * 64;
      if (pos == 1) continue;
      float* dst = tok + ((size_t)b * GG + pos) * EDD + o0;
#pragma unroll
      for (int oo = 0; oo < 8; ++oo) dst[oo] = acc[oo];
    }
  }
}

extern "C" void kernel_launch(void* const* d_in, const int* in_sizes, int n_in,
                              void* d_out, int out_size, void* d_ws, size_t ws_size,
                              hipStream_t stream) {
  const float* points = (const float*)d_in[0];
  const float* w1  = (const float*)d_in[1];
  const float* b1  = (const float*)d_in[2];
  const float* g1  = (const float*)d_in[3];
  const float* be1 = (const float*)d_in[4];
  const float* m1  = (const float*)d_in[5];
  const float* v1  = (const float*)d_in[6];
  const float* w2  = (const float*)d_in[7];
  const float* b2  = (const float*)d_in[8];
  const float* w3  = (const float*)d_in[9];
  const float* b3  = (const float*)d_in[10];
  const float* g2  = (const float*)d_in[11];
  const float* be2 = (const float*)d_in[12];
  const float* m2  = (const float*)d_in[13];
  const float* v2  = (const float*)d_in[14];
  const float* w4  = (const float*)d_in[15];
  const float* b4  = (const float*)d_in[16];
  float* out = (float*)d_out;
  float* ws  = (float*)d_ws;

  // dynamic LDS >64KB needs the opt-in attr (host-side, graph-safe, idempotent)
  size_t dyn_fps = (size_t)FPS_LDS_FLOATS * sizeof(float);
  size_t dyn_grp = (size_t)(NN + 64 + KK * 3 + 16) * sizeof(float);
  hipFuncSetAttribute(reinterpret_cast<const void*>(k_fps),
                      hipFuncAttributeMaxDynamicSharedMemorySize, (int)dyn_fps);
  hipFuncSetAttribute(reinterpret_cast<const void*>(k_grp),
                      hipFuncAttributeMaxDynamicSharedMemorySize, (int)dyn_grp);

  // invalidate k_fps sync slots (0xAA = top bit set = invalid); graph-safe.
  hipMemsetAsync(ws + WS_SYNC, 0xAA, (size_t)128 * 16 * 4 * 8, stream);

  hipLaunchKernelGGL(k_fps, dim3(BB * SB), dim3(NT1), dyn_fps, stream,
                     points, out, ws);
  hipLaunchKernelGGL(k_grp, dim3(32), dim3(NT1), dyn_grp, stream,
                     points, ws, w1, b1, g1, be1, m1, v1, w2, b2);
  hipLaunchKernelGGL(k_encB, dim3(256), dim3(256), 0, stream,
                     ws, w3, b3, g2, be2, m2, v2);
  hipLaunchKernelGGL(k_encCb, dim3(384), dim3(256), 0, stream, ws, w4, b4, out);
}